// Round 1
// 502.709 us; speedup vs baseline: 1.2303x; 1.2303x over previous
//
#include <hip/hip_runtime.h>
#include <math.h>

#define B_   64
#define N_   196
#define VD_  512
#define ED_  512
#define HD_  512
#define V_   10000
#define T_   20
#define G4_  2048   // 4*HD
#define LSTM_NBLK 32

typedef __attribute__((ext_vector_type(8))) short bf16x8;
typedef __attribute__((ext_vector_type(4))) float f32x4;

static __device__ __forceinline__ float sigmoidf_(float x) {
  return 1.f / (1.f + __expf(-x));
}

static __device__ __forceinline__ float tanh_fast(float x) {
  // 1 - 2/(e^{2x}+1); saturates correctly at +/-1, error << bf16 rounding
  float e = __expf(2.f * x);
  return 1.f - 2.f / (e + 1.f);
}

static __device__ __forceinline__ unsigned short f2bf_(float x) {
  unsigned u = __float_as_uint(x);
  unsigned r = (u + 0x7FFFu + ((u >> 16) & 1u)) >> 16;   // RNE
  return (unsigned short)r;
}

// ---------------------------------------------------------------------------
// k_prep: all fp32->bf16 casts + embedding gather-cast + attention logits,
// one launch (independent segments by blockIdx):
//   seg0 [0,5000):    W_out [10000][512]   -> wout_bf
//   seg1 [5000,6024): W_ih[:,512:1024]     -> wihe_bf [2048][512]
//   seg2 [6024,6664): embed[captions[b,t]] -> emb_bf  [t*64+b][512]
//   seg3 [6664,7688): W_hh  [2048][512]    -> whh_bf
//   seg4 [7688,7944): svg[b][n] = feat[b,n,:] . W_av   (attn logits;
//                     att_h/b_av/b_ah cancel in softmax over n)
// ---------------------------------------------------------------------------
__global__ void k_prep(const float* __restrict__ W_out,
                       const float* __restrict__ W_ih,
                       const float* __restrict__ W_hh,
                       const float* __restrict__ embed,
                       const int* __restrict__ caps,
                       const float* __restrict__ feat,
                       const float* __restrict__ W_av,
                       unsigned short* __restrict__ wout_bf,
                       unsigned short* __restrict__ wihe_bf,
                       unsigned short* __restrict__ whh_bf,
                       unsigned short* __restrict__ emb_bf,
                       float* __restrict__ svg) {
  int bx = blockIdx.x, tid = threadIdx.x;
  if (bx >= 7688) {   // attn1 segment
    int r = bx - 7688;
    int b = r >> 2, q = r & 3;
    int lane = tid & 63, w = tid >> 6;
    const float* fb = feat + (size_t)b * (N_ * VD_);
    float4 wv0 = *(const float4*)(W_av + lane * 8);
    float4 wv1 = *(const float4*)(W_av + lane * 8 + 4);
    int nbase = q * 49;
    for (int n = nbase + w; n < nbase + 49; n += 4) {
      const float* fp = fb + n * VD_ + lane * 8;
      float4 f0 = *(const float4*)fp;
      float4 f1 = *(const float4*)(fp + 4);
      float p = f0.x * wv0.x + f0.y * wv0.y + f0.z * wv0.z + f0.w * wv0.w
              + f1.x * wv1.x + f1.y * wv1.y + f1.z * wv1.z + f1.w * wv1.w;
#pragma unroll
      for (int off = 32; off > 0; off >>= 1) p += __shfl_down(p, off, 64);
      if (lane == 0) svg[b * N_ + n] = p;
    }
    return;
  }
  float4 v; unsigned short* dst; int i;
  if (bx < 5000) {
    i = bx * 256 + tid;
    v = ((const float4*)W_out)[i];
    dst = wout_bf;
  } else if (bx < 6024) {
    i = (bx - 5000) * 256 + tid;
    int j = i >> 7, kk = (i & 127) << 2;
    v = *(const float4*)(W_ih + (size_t)j * (VD_ + ED_) + VD_ + kk);
    dst = wihe_bf;
  } else if (bx < 6664) {
    i = (bx - 6024) * 256 + tid;
    int row = i >> 7;                          // t*64+b
    int b = row & 63, t = row >> 6;
    v = *(const float4*)(embed + (size_t)caps[b * T_ + t] * ED_ + ((i & 127) << 2));
    dst = emb_bf;
  } else {
    i = (bx - 6664) * 256 + tid;
    v = ((const float4*)W_hh)[i];
    dst = whh_bf;
  }
  ushort4 o;
  o.x = f2bf_(v.x); o.y = f2bf_(v.y); o.z = f2bf_(v.z); o.w = f2bf_(v.w);
  ((ushort4*)dst)[i] = o;
}

// ---------------------------------------------------------------------------
// k_attn2: softmax(svg[b]) -> weights; ctx + fmean for a 128-dim chunk.
// grid (64 b, 4 d-chunks). Second features read is L2/L3-hot.
// ---------------------------------------------------------------------------
__global__ void k_attn2(const float* __restrict__ feat,
                        const float* __restrict__ svg,
                        float* __restrict__ fmean,
                        float* __restrict__ ctx) {
  __shared__ float sa[200];
  __shared__ float red[8];
  __shared__ float pc[2][128];
  __shared__ float pf[2][128];
  int b = blockIdx.x, q = blockIdx.y;
  int tid = threadIdx.x, lane = tid & 63, w = tid >> 6;
  const float* fb = feat + (size_t)b * (N_ * VD_);

  float v = (tid < N_) ? svg[b * N_ + tid] : -1e30f;
  float m = v;
#pragma unroll
  for (int off = 32; off > 0; off >>= 1) m = fmaxf(m, __shfl_down(m, off, 64));
  if (lane == 0) red[w] = m;
  __syncthreads();
  m = fmaxf(fmaxf(red[0], red[1]), fmaxf(red[2], red[3]));

  float e = (tid < N_) ? __expf(v - m) : 0.f;
  float s = e;
#pragma unroll
  for (int off = 32; off > 0; off >>= 1) s += __shfl_down(s, off, 64);
  if (lane == 0) red[4 + w] = s;
  __syncthreads();
  float inv = 1.f / (red[4] + red[5] + red[6] + red[7]);
  if (tid < N_) sa[tid] = e * inv;
  __syncthreads();

  int d = q * 128 + (tid & 127);
  int nh = tid >> 7;
  float c = 0.f, fs = 0.f;
  for (int n = nh; n < N_; n += 2) {
    float f = fb[n * VD_ + d];
    c += sa[n] * f;
    fs += f;
  }
  pc[nh][tid & 127] = c;
  pf[nh][tid & 127] = fs;
  __syncthreads();
  if (tid < 128) {
    ctx[b * VD_ + q * 128 + tid] = pc[0][tid] + pc[1][tid];
    fmean[b * VD_ + q * 128 + tid] = (pf[0][tid] + pf[1][tid]) * (1.f / N_);
  }
}

// ---------------------------------------------------------------------------
// k_small: three M=64 fp32 GEMMs in one launch (48 blocks):
//   bx 0..7  : h0   = fmean @ W_init_h^T   (+ bf16 copy for step 0)
//   bx 8..15 : c0   = fmean @ W_init_c^T
//   bx 16..47: gctx = ctx @ W_ih[:, :VD]^T + b_ih + b_hh
// ---------------------------------------------------------------------------
#define BK 16
__global__ __launch_bounds__(256) void k_small(
    const float* __restrict__ fmean, const float* __restrict__ ctx,
    const float* __restrict__ W_init_h, const float* __restrict__ W_init_c,
    const float* __restrict__ W_ih,
    const float* __restrict__ b_ih, const float* __restrict__ b_hh,
    float* __restrict__ hbuf, float* __restrict__ cbuf, float* __restrict__ gctx,
    unsigned short* __restrict__ h0_bf) {
  const float* A; const float* Bw; float* C;
  int ldb, ldc, n0;
  const float* bias1 = nullptr; const float* bias2 = nullptr;
  unsigned short* hb = nullptr;
  int bx = blockIdx.x;
  if (bx < 8)       { A = fmean; Bw = W_init_h; C = hbuf; ldb = VD_; ldc = HD_; n0 = bx * 64; hb = h0_bf; }
  else if (bx < 16) { A = fmean; Bw = W_init_c; C = cbuf; ldb = VD_; ldc = HD_; n0 = (bx - 8) * 64; }
  else { A = ctx; Bw = W_ih; C = gctx; ldb = VD_ + ED_; ldc = G4_; n0 = (bx - 16) * 64;
         bias1 = b_ih; bias2 = b_hh; }

  __shared__ float As[BK][64];
  __shared__ float Bs[BK][64];
  int tid = threadIdx.x;
  int tm = tid & 15, tn = tid >> 4;
  int sr = tid >> 2, sk = (tid & 3) * 4;
  const float* arow = A + (size_t)sr * VD_;
  const float* brow = Bw + (size_t)(n0 + sr) * ldb;
  float acc[4][4] = {};

  for (int k0 = 0; k0 < VD_; k0 += BK) {
    float4 av = *(const float4*)(arow + k0 + sk);
    float4 bv = *(const float4*)(brow + k0 + sk);
    __syncthreads();
    As[sk + 0][sr] = av.x; As[sk + 1][sr] = av.y;
    As[sk + 2][sr] = av.z; As[sk + 3][sr] = av.w;
    Bs[sk + 0][sr] = bv.x; Bs[sk + 1][sr] = bv.y;
    Bs[sk + 2][sr] = bv.z; Bs[sk + 3][sr] = bv.w;
    __syncthreads();
#pragma unroll
    for (int kk = 0; kk < BK; ++kk) {
      float4 a4 = *(const float4*)&As[kk][tm * 4];
      float4 b4 = *(const float4*)&Bs[kk][tn * 4];
      acc[0][0] += a4.x * b4.x; acc[0][1] += a4.x * b4.y; acc[0][2] += a4.x * b4.z; acc[0][3] += a4.x * b4.w;
      acc[1][0] += a4.y * b4.x; acc[1][1] += a4.y * b4.y; acc[1][2] += a4.y * b4.z; acc[1][3] += a4.y * b4.w;
      acc[2][0] += a4.z * b4.x; acc[2][1] += a4.z * b4.y; acc[2][2] += a4.z * b4.z; acc[2][3] += a4.z * b4.w;
      acc[3][0] += a4.w * b4.x; acc[3][1] += a4.w * b4.y; acc[3][2] += a4.w * b4.z; acc[3][3] += a4.w * b4.w;
    }
  }
#pragma unroll
  for (int j = 0; j < 4; ++j) {
    int n = n0 + tn * 4 + j;
    float bb = (bias1 ? bias1[n] + bias2[n] : 0.f);
#pragma unroll
    for (int i = 0; i < 4; ++i) {
      int mm = tm * 4 + i;
      float val = acc[i][j] + bb;
      C[(size_t)mm * ldc + n] = val;
      if (hb) hb[(size_t)mm * HD_ + n] = f2bf_(val);
    }
  }
}

// ---------------------------------------------------------------------------
// Staged bf16 MFMA GEMM: C[M,N] = A[M,K]@Bw[N,K]^T (+bias[n]) (+radd[m&63,n]).
// 128x128 block tile, BK=32, LDS-staged, 4 waves 2x2.
// ---------------------------------------------------------------------------
__global__ __launch_bounds__(256) void k_gemm_mfma(
    const unsigned short* __restrict__ A,
    const unsigned short* __restrict__ Bw,
    const float* __restrict__ bias,
    const float* __restrict__ radd, int ldr,
    float* __restrict__ C, int M, int Nn, int K) {
  __shared__ unsigned short As[128][32];
  __shared__ unsigned short Bs[128][32];
  int tid = threadIdx.x;
  int wave = tid >> 6, lane = tid & 63;
  int wm = wave & 1, wn = wave >> 1;
  int m0 = blockIdx.y * 128, n0 = blockIdx.x * 128;
  int l15 = lane & 15, quad = lane >> 4;
  int sr = tid >> 1, skq = (tid & 1) * 16;
  const unsigned short* ga = A + (size_t)(m0 + sr) * K + skq;
  int bn = n0 + sr; if (bn >= Nn) bn = Nn - 1;
  const unsigned short* gb = Bw + (size_t)bn * K + skq;

  f32x4 acc[4][4];
#pragma unroll
  for (int i = 0; i < 4; ++i)
#pragma unroll
    for (int j = 0; j < 4; ++j) acc[i][j] = (f32x4){0.f, 0.f, 0.f, 0.f};

  for (int k0 = 0; k0 < K; k0 += 32) {
    bf16x8 a0 = *(const bf16x8*)(ga + k0);
    bf16x8 a1 = *(const bf16x8*)(ga + k0 + 8);
    bf16x8 b0 = *(const bf16x8*)(gb + k0);
    bf16x8 b1 = *(const bf16x8*)(gb + k0 + 8);
    __syncthreads();
    *(bf16x8*)&As[sr][skq] = a0; *(bf16x8*)&As[sr][skq + 8] = a1;
    *(bf16x8*)&Bs[sr][skq] = b0; *(bf16x8*)&Bs[sr][skq + 8] = b1;
    __syncthreads();
    bf16x8 af[4], bfr[4];
#pragma unroll
    for (int mt = 0; mt < 4; ++mt)
      af[mt] = *(const bf16x8*)&As[wm * 64 + mt * 16 + l15][quad * 8];
#pragma unroll
    for (int nt = 0; nt < 4; ++nt)
      bfr[nt] = *(const bf16x8*)&Bs[wn * 64 + nt * 16 + l15][quad * 8];
#pragma unroll
    for (int mt = 0; mt < 4; ++mt)
#pragma unroll
      for (int nt = 0; nt < 4; ++nt)
        acc[mt][nt] = __builtin_amdgcn_mfma_f32_16x16x32_bf16(af[mt], bfr[nt], acc[mt][nt], 0, 0, 0);
  }

#pragma unroll
  for (int nt = 0; nt < 4; ++nt) {
    int n = n0 + wn * 64 + nt * 16 + l15;
    if (n < Nn) {
      float bb = bias ? bias[n] : 0.f;
#pragma unroll
      for (int mt = 0; mt < 4; ++mt) {
        int mbase = m0 + wm * 64 + mt * 16 + quad * 4;
#pragma unroll
        for (int r = 0; r < 4; ++r) {
          int mg = mbase + r;
          float ra = radd ? radd[(size_t)(mg & 63) * ldr + n] : 0.f;
          C[(size_t)mg * Nn + n] = acc[mt][nt][r] + bb + ra;
        }
      }
    }
  }
}

// ---------------------------------------------------------------------------
// Persistent MFMA LSTM v2: all 20 steps, ONE launch, 32 blocks x 256 thr.
// Restructured to cut the per-step latency chain (was 13.4 us/step at <2%
// util on every pipe):
//   - wave w owns batch tile [16w,16w+16) and computes ALL FOUR gates for it
//     (acc[nt] = gate nt). i/f/g/o for a given (b,hid) land in ONE thread's
//     accumulator regs -> the old gs[] LDS recombine + 2 syncthreads vanish.
//   - W_hh block slice (4 gates x 16 cols x 512) staged ONCE into 64KB LDS,
//     XOR-swizzled (granule g' = g ^ (row&7): 2-way bank alias = free), read
//     as ds_read_b128 B-operands every step. Zero per-step weight traffic.
//   - h loads deduped 4x -> 1x (wave loads only its own 16 rows) and issued
//     as 16 independent dwordx4 loads before the MFMA chain (one L3 RT).
//   - gpre[t+1] prefetched into 16 regs right after the grid barrier ->
//     hidden under the next MFMA phase instead of sitting on the chain.
//   - release/acquire fences by tid0 only (L1 is write-through; syncthreads'
//     implicit vmcnt(0) drains all waves' stores to the shared L2, one
//     buffer_wbl2 publishes them).
// c lives in registers; h ping-pongs through hall_bf (fresh address per t,
// so readers always miss L2 and pick up the flushed data).
// ---------------------------------------------------------------------------
__global__ __launch_bounds__(256, 1) void k_lstm_mfma(
    const unsigned short* __restrict__ whh_bf,   // [2048][512] bf16
    const float* __restrict__ gpre,              // [T*64][2048]
    const unsigned short* __restrict__ h0_bf,    // [64][512] bf16
    const float* __restrict__ c0,                // [64][512] fp32
    unsigned short* __restrict__ hall_bf,        // [T][64][512] bf16
    int* __restrict__ bar) {
  __shared__ unsigned short whh_s[64 * 512];     // 64KB, swizzled
  int tid = threadIdx.x;
  int w = tid >> 6, lane = tid & 63;
  int l15 = lane & 15, quad = lane >> 4;
  int n0 = blockIdx.x * 16;

  // ---- stage whh slice into LDS, one-time, XOR-swizzled ----
  // LDS row r (= gate*16 + l) granule g' holds global granule g' ^ (r&7).
  for (int idx = tid; idx < 4096; idx += 256) {
    int r = idx >> 6, gg = idx & 63;
    int gate = r >> 4, l = r & 15;
    bf16x8 v = *(const bf16x8*)(whh_bf +
        (size_t)(gate * HD_ + n0 + l) * HD_ + gg * 8);
    *(bf16x8*)&whh_s[r * 512 + (gg ^ (r & 7)) * 8] = v;
  }

  // thread owns (b = brow + r, hid = n0 + l15), r = 0..3  (matches MFMA D)
  int brow = w * 16 + quad * 4;

  float c_reg[4];
#pragma unroll
  for (int r = 0; r < 4; ++r)
    c_reg[r] = c0[(size_t)(brow + r) * HD_ + n0 + l15];

  // prefetch gpre for t=0
  float gr[16];
#pragma unroll
  for (int g = 0; g < 4; ++g)
#pragma unroll
    for (int r = 0; r < 4; ++r)
      gr[g * 4 + r] = gpre[(size_t)(brow + r) * G4_ + g * HD_ + n0 + l15];

  __syncthreads();   // whh_s ready

  for (int t = 0; t < T_; ++t) {
    const unsigned short* h_in =
        (t == 0) ? h0_bf : (hall_bf + (size_t)(t - 1) * B_ * HD_);
    const unsigned short* ar = h_in + (size_t)(w * 16 + l15) * HD_ + quad * 8;

    // batch all 16 A loads (independent, one L3 round-trip covers all)
    bf16x8 a[16];
#pragma unroll
    for (int ki = 0; ki < 16; ++ki) a[ki] = *(const bf16x8*)(ar + ki * 32);

    f32x4 acc[4];
#pragma unroll
    for (int i = 0; i < 4; ++i) acc[i] = (f32x4){0.f, 0.f, 0.f, 0.f};

#pragma unroll
    for (int ki = 0; ki < 16; ++ki) {
      int rb = l15 * 512 + (((ki * 4 + quad) ^ (l15 & 7)) << 3);
#pragma unroll
      for (int nt = 0; nt < 4; ++nt) {
        bf16x8 b = *(const bf16x8*)&whh_s[nt * 16 * 512 + rb];
        acc[nt] = __builtin_amdgcn_mfma_f32_16x16x32_bf16(a[ki], b, acc[nt], 0, 0, 0);
      }
    }

    // elementwise: all four gates for (brow+r, n0+l15) are in this thread
    unsigned short* hout = hall_bf + (size_t)t * B_ * HD_;
#pragma unroll
    for (int r = 0; r < 4; ++r) {
      float gi = acc[0][r] + gr[0 + r];
      float gf = acc[1][r] + gr[4 + r];
      float gg = acc[2][r] + gr[8 + r];
      float go = acc[3][r] + gr[12 + r];
      float cn = sigmoidf_(gf) * c_reg[r] + sigmoidf_(gi) * tanh_fast(gg);
      c_reg[r] = cn;
      hout[(size_t)(brow + r) * HD_ + n0 + l15] =
          f2bf_(sigmoidf_(go) * tanh_fast(cn));
    }

    if (t < T_ - 1) {
      __syncthreads();          // implicit vmcnt(0): all waves' h stores in L2
      if (tid == 0) {
        __threadfence();        // wbL2: publish this block's h slice
        atomicAdd(bar, 1);
        int target = (t + 1) * LSTM_NBLK;
        while (__hip_atomic_load(bar, __ATOMIC_RELAXED,
                                 __HIP_MEMORY_SCOPE_AGENT) < target)
          __builtin_amdgcn_s_sleep(2);
        __threadfence();        // acquire: invalidate for fresh h
      }
      __syncthreads();
      // prefetch gpre for t+1 — hidden under next step's h-load + MFMA phase
      const float* gpt = gpre + (size_t)(t + 1) * B_ * G4_;
#pragma unroll
      for (int g = 0; g < 4; ++g)
#pragma unroll
        for (int r = 0; r < 4; ++r)
          gr[g * 4 + r] = gpt[(size_t)(brow + r) * G4_ + g * HD_ + n0 + l15];
    }
  }
}

// ---------------------------------------------------------------------------
// Fused log_softmax + softmax per row of logits [1280][10000] (softmax in
// place; log_softmax to out1).
// ---------------------------------------------------------------------------
__global__ void k_softmax(float* __restrict__ logits, float* __restrict__ out1) {
  __shared__ float red[8];
  int row = blockIdx.x, tid = threadIdx.x;
  int lane = tid & 63, wid = tid >> 6;
  float* lr = logits + (size_t)row * V_;
  float* o1 = out1 + (size_t)row * V_;
  const int NV4 = V_ / 4;  // 2500

  float m = -1e30f;
  for (int i = tid; i < NV4; i += 256) {
    float4 v = ((const float4*)lr)[i];
    m = fmaxf(m, fmaxf(fmaxf(v.x, v.y), fmaxf(v.z, v.w)));
  }
#pragma unroll
  for (int off = 32; off > 0; off >>= 1) m = fmaxf(m, __shfl_down(m, off, 64));
  if (lane == 0) red[4 + wid] = m;
  __syncthreads();
  m = fmaxf(fmaxf(red[4], red[5]), fmaxf(red[6], red[7]));

  float s = 0.f;
  for (int i = tid; i < NV4; i += 256) {
    float4 v = ((const float4*)lr)[i];
    s += __expf(v.x - m) + __expf(v.y - m) + __expf(v.z - m) + __expf(v.w - m);
  }
#pragma unroll
  for (int off = 32; off > 0; off >>= 1) s += __shfl_down(s, off, 64);
  if (lane == 0) red[wid] = s;
  __syncthreads();
  s = red[0] + red[1] + red[2] + red[3];
  float ls = __logf(s), inv = 1.f / s;

  for (int i = tid; i < NV4; i += 256) {
    float4 v = ((const float4*)lr)[i];
    float4 a, bb;
    a.x = v.x - m - ls; a.y = v.y - m - ls; a.z = v.z - m - ls; a.w = v.w - m - ls;
    bb.x = __expf(v.x - m) * inv; bb.y = __expf(v.y - m) * inv;
    bb.z = __expf(v.z - m) * inv; bb.w = __expf(v.w - m) * inv;
    ((float4*)o1)[i] = a;
    ((float4*)lr)[i] = bb;
  }
}

// ---------------------------------------------------------------------------
extern "C" void kernel_launch(void* const* d_in, const int* in_sizes, int n_in,
                              void* d_out, int out_size, void* d_ws, size_t ws_size,
                              hipStream_t stream) {
  const float* features = (const float*)d_in[0];
  const int*   captions = (const int*)d_in[1];
  const float* W_init_h = (const float*)d_in[2];
  const float* W_init_c = (const float*)d_in[3];
  const float* W_av     = (const float*)d_in[4];
  // d_in[5] b_av, d_in[6] W_ah, d_in[7] b_ah: cancel inside softmax over n.
  const float* embed    = (const float*)d_in[8];
  const float* W_ih     = (const float*)d_in[9];
  const float* W_hh     = (const float*)d_in[10];
  const float* b_ih     = (const float*)d_in[11];
  const float* b_hh     = (const float*)d_in[12];
  const float* W_out    = (const float*)d_in[13];
  const float* b_out    = (const float*)d_in[14];

  float* ws    = (float*)d_ws;
  float* fmean = ws;                             // 32768
  float* ctx   = fmean + B_ * VD_;               // 32768
  float* hbuf  = ctx + B_ * VD_;                 // 32768 (fp32 h0)
  float* cbuf  = hbuf + B_ * HD_;                // 32768 (c0)
  float* gctx  = cbuf + B_ * HD_;                // 131072
  float* svg   = gctx + (size_t)B_ * G4_;        // 12544 -> pad 12608
  float* gpre  = svg + 12608;                    // 2,621,440
  int*   bar   = (int*)(gpre + (size_t)T_ * B_ * G4_);                       // 64 ints
  unsigned short* wout_bf = (unsigned short*)(bar + 64);                     // 5,120,000
  unsigned short* wihe_bf = wout_bf + (size_t)V_ * HD_;                      // 1,048,576
  unsigned short* whh_bf  = wihe_bf + (size_t)G4_ * ED_;                     // 1,048,576
  unsigned short* emb_bf  = whh_bf + (size_t)G4_ * HD_;                      // 655,360
  unsigned short* h0_bf   = emb_bf + (size_t)T_ * B_ * ED_;                  // 32,768
  unsigned short* hall_bf = h0_bf + (size_t)B_ * HD_;                        // 655,360
  // total ~28.8 MB

  float* out1   = (float*)d_out;                     // log_softmax [T,B,V]
  float* logits = out1 + (size_t)T_ * B_ * V_;       // softmax slot = scratch

  hipMemsetAsync(bar, 0, 256, stream);

  k_prep<<<7944, 256, 0, stream>>>(W_out, W_ih, W_hh, embed, captions,
                                   features, W_av,
                                   wout_bf, wihe_bf, whh_bf, emb_bf, svg);
  k_attn2<<<dim3(B_, 4), 256, 0, stream>>>(features, svg, fmean, ctx);
  k_small<<<48, 256, 0, stream>>>(fmean, ctx, W_init_h, W_init_c, W_ih,
                                  b_ih, b_hh, hbuf, cbuf, gctx, h0_bf);

  // gpre[t*64+b, :] = emb_bf @ wihe_bf^T + gctx[b, :]  (gctx includes biases)
  k_gemm_mfma<<<dim3(G4_ / 128, (T_ * B_) / 128), 256, 0, stream>>>(
      emb_bf, wihe_bf, nullptr, gctx, G4_, gpre, T_ * B_, G4_, ED_);

  // all 20 LSTM steps, ONE launch (32-block persistent, load-spin barrier)
  k_lstm_mfma<<<LSTM_NBLK, 256, 0, stream>>>(
      whh_bf, gpre, h0_bf, cbuf, hall_bf, bar);

  // logits = hall @ W_out^T + b_out  (bf16 MFMA, fp32 accumulate)
  k_gemm_mfma<<<dim3((V_ + 127) / 128, (T_ * B_) / 128), 256, 0, stream>>>(
      hall_bf, wout_bf, b_out, nullptr, 0, logits, T_ * B_, V_, HD_);

  k_softmax<<<T_ * B_, 256, 0, stream>>>(logits, out1);
}

// Round 2
// 469.596 us; speedup vs baseline: 1.3170x; 1.0705x over previous
//
#include <hip/hip_runtime.h>
#include <math.h>

#define B_   64
#define N_   196
#define VD_  512
#define ED_  512
#define HD_  512
#define V_   10000
#define T_   20
#define G4_  2048   // 4*HD
#define LSTM_NBLK 32

typedef __attribute__((ext_vector_type(8))) short bf16x8;
typedef __attribute__((ext_vector_type(4))) float f32x4;

static __device__ __forceinline__ float sigmoidf_(float x) {
  return 1.f / (1.f + __expf(-x));
}

static __device__ __forceinline__ float tanh_fast(float x) {
  // 1 - 2/(e^{2x}+1); saturates correctly at +/-1, error << bf16 rounding
  float e = __expf(2.f * x);
  return 1.f - 2.f / (e + 1.f);
}

static __device__ __forceinline__ unsigned short f2bf_(float x) {
  unsigned u = __float_as_uint(x);
  unsigned r = (u + 0x7FFFu + ((u >> 16) & 1u)) >> 16;   // RNE
  return (unsigned short)r;
}

// ---------------------------------------------------------------------------
// k_prep: all fp32->bf16 casts + embedding gather-cast + attention logits,
// one launch (independent segments by blockIdx):
//   seg0 [0,5000):    W_out [10000][512]   -> wout_bf
//   seg1 [5000,6024): W_ih[:,512:1024]     -> wihe_bf [2048][512]
//   seg2 [6024,6664): embed[captions[b,t]] -> emb_bf  [t*64+b][512]
//   seg3 [6664,7688): W_hh  [2048][512]    -> whh_bf
//   seg4 [7688,7944): svg[b][n] = feat[b,n,:] . W_av   (attn logits;
//                     att_h/b_av/b_ah cancel in softmax over n)
// ---------------------------------------------------------------------------
__global__ void k_prep(const float* __restrict__ W_out,
                       const float* __restrict__ W_ih,
                       const float* __restrict__ W_hh,
                       const float* __restrict__ embed,
                       const int* __restrict__ caps,
                       const float* __restrict__ feat,
                       const float* __restrict__ W_av,
                       unsigned short* __restrict__ wout_bf,
                       unsigned short* __restrict__ wihe_bf,
                       unsigned short* __restrict__ whh_bf,
                       unsigned short* __restrict__ emb_bf,
                       float* __restrict__ svg) {
  int bx = blockIdx.x, tid = threadIdx.x;
  if (bx >= 7688) {   // attn1 segment
    int r = bx - 7688;
    int b = r >> 2, q = r & 3;
    int lane = tid & 63, w = tid >> 6;
    const float* fb = feat + (size_t)b * (N_ * VD_);
    float4 wv0 = *(const float4*)(W_av + lane * 8);
    float4 wv1 = *(const float4*)(W_av + lane * 8 + 4);
    int nbase = q * 49;
    for (int n = nbase + w; n < nbase + 49; n += 4) {
      const float* fp = fb + n * VD_ + lane * 8;
      float4 f0 = *(const float4*)fp;
      float4 f1 = *(const float4*)(fp + 4);
      float p = f0.x * wv0.x + f0.y * wv0.y + f0.z * wv0.z + f0.w * wv0.w
              + f1.x * wv1.x + f1.y * wv1.y + f1.z * wv1.z + f1.w * wv1.w;
#pragma unroll
      for (int off = 32; off > 0; off >>= 1) p += __shfl_down(p, off, 64);
      if (lane == 0) svg[b * N_ + n] = p;
    }
    return;
  }
  float4 v; unsigned short* dst; int i;
  if (bx < 5000) {
    i = bx * 256 + tid;
    v = ((const float4*)W_out)[i];
    dst = wout_bf;
  } else if (bx < 6024) {
    i = (bx - 5000) * 256 + tid;
    int j = i >> 7, kk = (i & 127) << 2;
    v = *(const float4*)(W_ih + (size_t)j * (VD_ + ED_) + VD_ + kk);
    dst = wihe_bf;
  } else if (bx < 6664) {
    i = (bx - 6024) * 256 + tid;
    int row = i >> 7;                          // t*64+b
    int b = row & 63, t = row >> 6;
    v = *(const float4*)(embed + (size_t)caps[b * T_ + t] * ED_ + ((i & 127) << 2));
    dst = emb_bf;
  } else {
    i = (bx - 6664) * 256 + tid;
    v = ((const float4*)W_hh)[i];
    dst = whh_bf;
  }
  ushort4 o;
  o.x = f2bf_(v.x); o.y = f2bf_(v.y); o.z = f2bf_(v.z); o.w = f2bf_(v.w);
  ((ushort4*)dst)[i] = o;
}

// ---------------------------------------------------------------------------
// k_attn2: softmax(svg[b]) -> weights; ctx + fmean for a 128-dim chunk.
// grid (64 b, 4 d-chunks). Second features read is L2/L3-hot.
// ---------------------------------------------------------------------------
__global__ void k_attn2(const float* __restrict__ feat,
                        const float* __restrict__ svg,
                        float* __restrict__ fmean,
                        float* __restrict__ ctx) {
  __shared__ float sa[200];
  __shared__ float red[8];
  __shared__ float pc[2][128];
  __shared__ float pf[2][128];
  int b = blockIdx.x, q = blockIdx.y;
  int tid = threadIdx.x, lane = tid & 63, w = tid >> 6;
  const float* fb = feat + (size_t)b * (N_ * VD_);

  float v = (tid < N_) ? svg[b * N_ + tid] : -1e30f;
  float m = v;
#pragma unroll
  for (int off = 32; off > 0; off >>= 1) m = fmaxf(m, __shfl_down(m, off, 64));
  if (lane == 0) red[w] = m;
  __syncthreads();
  m = fmaxf(fmaxf(red[0], red[1]), fmaxf(red[2], red[3]));

  float e = (tid < N_) ? __expf(v - m) : 0.f;
  float s = e;
#pragma unroll
  for (int off = 32; off > 0; off >>= 1) s += __shfl_down(s, off, 64);
  if (lane == 0) red[4 + w] = s;
  __syncthreads();
  float inv = 1.f / (red[4] + red[5] + red[6] + red[7]);
  if (tid < N_) sa[tid] = e * inv;
  __syncthreads();

  int d = q * 128 + (tid & 127);
  int nh = tid >> 7;
  float c = 0.f, fs = 0.f;
  for (int n = nh; n < N_; n += 2) {
    float f = fb[n * VD_ + d];
    c += sa[n] * f;
    fs += f;
  }
  pc[nh][tid & 127] = c;
  pf[nh][tid & 127] = fs;
  __syncthreads();
  if (tid < 128) {
    ctx[b * VD_ + q * 128 + tid] = pc[0][tid] + pc[1][tid];
    fmean[b * VD_ + q * 128 + tid] = (pf[0][tid] + pf[1][tid]) * (1.f / N_);
  }
}

// ---------------------------------------------------------------------------
// k_small: three M=64 fp32 GEMMs in one launch (48 blocks):
//   bx 0..7  : h0   = fmean @ W_init_h^T   (+ bf16 copy for step 0)
//   bx 8..15 : c0   = fmean @ W_init_c^T
//   bx 16..47: gctx = ctx @ W_ih[:, :VD]^T + b_ih + b_hh
// ---------------------------------------------------------------------------
#define BK 16
__global__ __launch_bounds__(256) void k_small(
    const float* __restrict__ fmean, const float* __restrict__ ctx,
    const float* __restrict__ W_init_h, const float* __restrict__ W_init_c,
    const float* __restrict__ W_ih,
    const float* __restrict__ b_ih, const float* __restrict__ b_hh,
    float* __restrict__ hbuf, float* __restrict__ cbuf, float* __restrict__ gctx,
    unsigned short* __restrict__ h0_bf) {
  const float* A; const float* Bw; float* C;
  int ldb, ldc, n0;
  const float* bias1 = nullptr; const float* bias2 = nullptr;
  unsigned short* hb = nullptr;
  int bx = blockIdx.x;
  if (bx < 8)       { A = fmean; Bw = W_init_h; C = hbuf; ldb = VD_; ldc = HD_; n0 = bx * 64; hb = h0_bf; }
  else if (bx < 16) { A = fmean; Bw = W_init_c; C = cbuf; ldb = VD_; ldc = HD_; n0 = (bx - 8) * 64; }
  else { A = ctx; Bw = W_ih; C = gctx; ldb = VD_ + ED_; ldc = G4_; n0 = (bx - 16) * 64;
         bias1 = b_ih; bias2 = b_hh; }

  __shared__ float As[BK][64];
  __shared__ float Bs[BK][64];
  int tid = threadIdx.x;
  int tm = tid & 15, tn = tid >> 4;
  int sr = tid >> 2, sk = (tid & 3) * 4;
  const float* arow = A + (size_t)sr * VD_;
  const float* brow = Bw + (size_t)(n0 + sr) * ldb;
  float acc[4][4] = {};

  for (int k0 = 0; k0 < VD_; k0 += BK) {
    float4 av = *(const float4*)(arow + k0 + sk);
    float4 bv = *(const float4*)(brow + k0 + sk);
    __syncthreads();
    As[sk + 0][sr] = av.x; As[sk + 1][sr] = av.y;
    As[sk + 2][sr] = av.z; As[sk + 3][sr] = av.w;
    Bs[sk + 0][sr] = bv.x; Bs[sk + 1][sr] = bv.y;
    Bs[sk + 2][sr] = bv.z; Bs[sk + 3][sr] = bv.w;
    __syncthreads();
#pragma unroll
    for (int kk = 0; kk < BK; ++kk) {
      float4 a4 = *(const float4*)&As[kk][tm * 4];
      float4 b4 = *(const float4*)&Bs[kk][tn * 4];
      acc[0][0] += a4.x * b4.x; acc[0][1] += a4.x * b4.y; acc[0][2] += a4.x * b4.z; acc[0][3] += a4.x * b4.w;
      acc[1][0] += a4.y * b4.x; acc[1][1] += a4.y * b4.y; acc[1][2] += a4.y * b4.z; acc[1][3] += a4.y * b4.w;
      acc[2][0] += a4.z * b4.x; acc[2][1] += a4.z * b4.y; acc[2][2] += a4.z * b4.z; acc[2][3] += a4.z * b4.w;
      acc[3][0] += a4.w * b4.x; acc[3][1] += a4.w * b4.y; acc[3][2] += a4.w * b4.z; acc[3][3] += a4.w * b4.w;
    }
  }
#pragma unroll
  for (int j = 0; j < 4; ++j) {
    int n = n0 + tn * 4 + j;
    float bb = (bias1 ? bias1[n] + bias2[n] : 0.f);
#pragma unroll
    for (int i = 0; i < 4; ++i) {
      int mm = tm * 4 + i;
      float val = acc[i][j] + bb;
      C[(size_t)mm * ldc + n] = val;
      if (hb) hb[(size_t)mm * HD_ + n] = f2bf_(val);
    }
  }
}

// ---------------------------------------------------------------------------
// Staged bf16 MFMA GEMM: C[M,N] = A[M,K]@Bw[N,K]^T (+bias[n]) (+radd[m&63,n]).
// 128x128 block tile, BK=32, LDS-staged, 4 waves 2x2.
// ---------------------------------------------------------------------------
__global__ __launch_bounds__(256) void k_gemm_mfma(
    const unsigned short* __restrict__ A,
    const unsigned short* __restrict__ Bw,
    const float* __restrict__ bias,
    const float* __restrict__ radd, int ldr,
    float* __restrict__ C, int M, int Nn, int K) {
  __shared__ unsigned short As[128][32];
  __shared__ unsigned short Bs[128][32];
  int tid = threadIdx.x;
  int wave = tid >> 6, lane = tid & 63;
  int wm = wave & 1, wn = wave >> 1;
  int m0 = blockIdx.y * 128, n0 = blockIdx.x * 128;
  int l15 = lane & 15, quad = lane >> 4;
  int sr = tid >> 1, skq = (tid & 1) * 16;
  const unsigned short* ga = A + (size_t)(m0 + sr) * K + skq;
  int bn = n0 + sr; if (bn >= Nn) bn = Nn - 1;
  const unsigned short* gb = Bw + (size_t)bn * K + skq;

  f32x4 acc[4][4];
#pragma unroll
  for (int i = 0; i < 4; ++i)
#pragma unroll
    for (int j = 0; j < 4; ++j) acc[i][j] = (f32x4){0.f, 0.f, 0.f, 0.f};

  for (int k0 = 0; k0 < K; k0 += 32) {
    bf16x8 a0 = *(const bf16x8*)(ga + k0);
    bf16x8 a1 = *(const bf16x8*)(ga + k0 + 8);
    bf16x8 b0 = *(const bf16x8*)(gb + k0);
    bf16x8 b1 = *(const bf16x8*)(gb + k0 + 8);
    __syncthreads();
    *(bf16x8*)&As[sr][skq] = a0; *(bf16x8*)&As[sr][skq + 8] = a1;
    *(bf16x8*)&Bs[sr][skq] = b0; *(bf16x8*)&Bs[sr][skq + 8] = b1;
    __syncthreads();
    bf16x8 af[4], bfr[4];
#pragma unroll
    for (int mt = 0; mt < 4; ++mt)
      af[mt] = *(const bf16x8*)&As[wm * 64 + mt * 16 + l15][quad * 8];
#pragma unroll
    for (int nt = 0; nt < 4; ++nt)
      bfr[nt] = *(const bf16x8*)&Bs[wn * 64 + nt * 16 + l15][quad * 8];
#pragma unroll
    for (int mt = 0; mt < 4; ++mt)
#pragma unroll
      for (int nt = 0; nt < 4; ++nt)
        acc[mt][nt] = __builtin_amdgcn_mfma_f32_16x16x32_bf16(af[mt], bfr[nt], acc[mt][nt], 0, 0, 0);
  }

#pragma unroll
  for (int nt = 0; nt < 4; ++nt) {
    int n = n0 + wn * 64 + nt * 16 + l15;
    if (n < Nn) {
      float bb = bias ? bias[n] : 0.f;
#pragma unroll
      for (int mt = 0; mt < 4; ++mt) {
        int mbase = m0 + wm * 64 + mt * 16 + quad * 4;
#pragma unroll
        for (int r = 0; r < 4; ++r) {
          int mg = mbase + r;
          float ra = radd ? radd[(size_t)(mg & 63) * ldr + n] : 0.f;
          C[(size_t)mg * Nn + n] = acc[mt][nt][r] + bb + ra;
        }
      }
    }
  }
}

// ---------------------------------------------------------------------------
// Persistent MFMA LSTM v3: all 20 steps, ONE launch, 32 blocks x 256 thr.
// v2 cut the step to 7.5us but the chain was still coherence machinery:
// wbL2 release fence + 32 same-address atomicAdds + full-L2 invalidate
// acquire + post-barrier gpre load. Nothing reused across steps lives in
// L2 (W_hh->LDS, c->regs, h/gpre->fresh addresses), so cache-wide
// maintenance buys nothing. v3 uses PER-ACCESS coherence:
//   - h stores/loads + flag stores with sc0 sc1 (write-through / read-from
//     the coherence point). NO threadfence at all.
//   - barrier = per-block flag store + one-load poll: lanes 0..31 of wave 0
//     each watch one block's flag (64B-strided) -> one global_load_dword
//     per poll round, no RMW serialization.
//   - gpre[t+1] prefetch issued between flag-store and poll -> latency
//     hides under the barrier wait.
// ---------------------------------------------------------------------------
__global__ __launch_bounds__(256, 1) void k_lstm_mfma(
    const unsigned short* __restrict__ whh_bf,   // [2048][512] bf16
    const float* __restrict__ gpre,              // [T*64][2048]
    const unsigned short* __restrict__ h0_bf,    // [64][512] bf16
    const float* __restrict__ c0,                // [64][512] fp32
    unsigned short* __restrict__ hall_bf,        // [T][64][512] bf16
    int* __restrict__ bar) {                     // [32*16] flags, 64B stride
  __shared__ unsigned short whh_s[64 * 512];     // 64KB, swizzled
  int tid = threadIdx.x;
  int w = tid >> 6, lane = tid & 63;
  int l15 = lane & 15, quad = lane >> 4;
  int n0 = blockIdx.x * 16;

  // ---- stage whh slice into LDS, one-time, XOR-swizzled ----
  for (int idx = tid; idx < 4096; idx += 256) {
    int r = idx >> 6, gg = idx & 63;
    int gate = r >> 4, l = r & 15;
    bf16x8 v = *(const bf16x8*)(whh_bf +
        (size_t)(gate * HD_ + n0 + l) * HD_ + gg * 8);
    *(bf16x8*)&whh_s[r * 512 + (gg ^ (r & 7)) * 8] = v;
  }

  // thread owns (b = brow + r, hid = n0 + l15), r = 0..3  (matches MFMA D)
  int brow = w * 16 + quad * 4;

  float c_reg[4];
#pragma unroll
  for (int r = 0; r < 4; ++r)
    c_reg[r] = c0[(size_t)(brow + r) * HD_ + n0 + l15];

  // prefetch gpre for t=0
  float gr[16];
#pragma unroll
  for (int g = 0; g < 4; ++g)
#pragma unroll
    for (int r = 0; r < 4; ++r)
      gr[g * 4 + r] = gpre[(size_t)(brow + r) * G4_ + g * HD_ + n0 + l15];

  __syncthreads();   // whh_s ready

  for (int t = 0; t < T_; ++t) {
    const unsigned short* h_in =
        (t == 0) ? h0_bf : (hall_bf + (size_t)(t - 1) * B_ * HD_);
    const unsigned short* ar = h_in + (size_t)(w * 16 + l15) * HD_ + quad * 8;

    // batch all 16 A loads, coherent (bypass L1/L2 -> coherence point).
    bf16x8 a[16];
#pragma unroll
    for (int ki = 0; ki < 16; ++ki)
      asm volatile("global_load_dwordx4 %0, %1, off sc0 sc1"
                   : "=v"(a[ki]) : "v"(ar + ki * 32) : "memory");
    asm volatile("s_waitcnt vmcnt(0)" ::: "memory");
    __builtin_amdgcn_sched_barrier(0);   // keep MFMAs below the waitcnt

    f32x4 acc[4];
#pragma unroll
    for (int i = 0; i < 4; ++i) acc[i] = (f32x4){0.f, 0.f, 0.f, 0.f};

#pragma unroll
    for (int ki = 0; ki < 16; ++ki) {
      int rb = l15 * 512 + (((ki * 4 + quad) ^ (l15 & 7)) << 3);
#pragma unroll
      for (int nt = 0; nt < 4; ++nt) {
        bf16x8 b = *(const bf16x8*)&whh_s[nt * 16 * 512 + rb];
        acc[nt] = __builtin_amdgcn_mfma_f32_16x16x32_bf16(a[ki], b, acc[nt], 0, 0, 0);
      }
    }

    // elementwise: all four gates for (brow+r, n0+l15) are in this thread
    unsigned short* hout = hall_bf + (size_t)t * B_ * HD_;
#pragma unroll
    for (int r = 0; r < 4; ++r) {
      float gi = acc[0][r] + gr[0 + r];
      float gf = acc[1][r] + gr[4 + r];
      float gg = acc[2][r] + gr[8 + r];
      float go = acc[3][r] + gr[12 + r];
      float cn = sigmoidf_(gf) * c_reg[r] + sigmoidf_(gi) * tanh_fast(gg);
      c_reg[r] = cn;
      unsigned hv = f2bf_(sigmoidf_(go) * tanh_fast(cn));
      unsigned short* sp = hout + (size_t)(brow + r) * HD_ + n0 + l15;
      asm volatile("global_store_short %0, %1, off sc0 sc1"
                   :: "v"(sp), "v"(hv) : "memory");
    }

    if (t < T_ - 1) {
      asm volatile("s_waitcnt vmcnt(0)" ::: "memory");  // h at coherence pt
      __syncthreads();                                  // all waves drained
      if (tid == 0) {
        int* fp = bar + blockIdx.x * 16;
        int fv = t + 1;
        asm volatile("global_store_dword %0, %1, off sc0 sc1"
                     :: "v"(fp), "v"(fv) : "memory");
      }
      // prefetch gpre for t+1 — overlaps the barrier wait
      const float* gpt = gpre + (size_t)(t + 1) * B_ * G4_;
#pragma unroll
      for (int g = 0; g < 4; ++g)
#pragma unroll
        for (int r = 0; r < 4; ++r)
          gr[g * 4 + r] = gpt[(size_t)(brow + r) * G4_ + g * HD_ + n0 + l15];
      if (tid < 64) {   // wave 0: lanes 0..31 watch one flag each
        int* fp = bar + (tid & 31) * 16;
        while (true) {
          int v = __hip_atomic_load(fp, __ATOMIC_RELAXED,
                                    __HIP_MEMORY_SCOPE_AGENT);
          if (__all(v >= t + 1)) break;
          __builtin_amdgcn_s_sleep(1);
        }
      }
      __syncthreads();
    }
  }
}

// ---------------------------------------------------------------------------
// Fused log_softmax + softmax per row of logits [1280][10000] (softmax in
// place; log_softmax to out1).
// ---------------------------------------------------------------------------
__global__ void k_softmax(float* __restrict__ logits, float* __restrict__ out1) {
  __shared__ float red[8];
  int row = blockIdx.x, tid = threadIdx.x;
  int lane = tid & 63, wid = tid >> 6;
  float* lr = logits + (size_t)row * V_;
  float* o1 = out1 + (size_t)row * V_;
  const int NV4 = V_ / 4;  // 2500

  float m = -1e30f;
  for (int i = tid; i < NV4; i += 256) {
    float4 v = ((const float4*)lr)[i];
    m = fmaxf(m, fmaxf(fmaxf(v.x, v.y), fmaxf(v.z, v.w)));
  }
#pragma unroll
  for (int off = 32; off > 0; off >>= 1) m = fmaxf(m, __shfl_down(m, off, 64));
  if (lane == 0) red[4 + wid] = m;
  __syncthreads();
  m = fmaxf(fmaxf(red[4], red[5]), fmaxf(red[6], red[7]));

  float s = 0.f;
  for (int i = tid; i < NV4; i += 256) {
    float4 v = ((const float4*)lr)[i];
    s += __expf(v.x - m) + __expf(v.y - m) + __expf(v.z - m) + __expf(v.w - m);
  }
#pragma unroll
  for (int off = 32; off > 0; off >>= 1) s += __shfl_down(s, off, 64);
  if (lane == 0) red[wid] = s;
  __syncthreads();
  s = red[0] + red[1] + red[2] + red[3];
  float ls = __logf(s), inv = 1.f / s;

  for (int i = tid; i < NV4; i += 256) {
    float4 v = ((const float4*)lr)[i];
    float4 a, bb;
    a.x = v.x - m - ls; a.y = v.y - m - ls; a.z = v.z - m - ls; a.w = v.w - m - ls;
    bb.x = __expf(v.x - m) * inv; bb.y = __expf(v.y - m) * inv;
    bb.z = __expf(v.z - m) * inv; bb.w = __expf(v.w - m) * inv;
    ((float4*)o1)[i] = a;
    ((float4*)lr)[i] = bb;
  }
}

// ---------------------------------------------------------------------------
extern "C" void kernel_launch(void* const* d_in, const int* in_sizes, int n_in,
                              void* d_out, int out_size, void* d_ws, size_t ws_size,
                              hipStream_t stream) {
  const float* features = (const float*)d_in[0];
  const int*   captions = (const int*)d_in[1];
  const float* W_init_h = (const float*)d_in[2];
  const float* W_init_c = (const float*)d_in[3];
  const float* W_av     = (const float*)d_in[4];
  // d_in[5] b_av, d_in[6] W_ah, d_in[7] b_ah: cancel inside softmax over n.
  const float* embed    = (const float*)d_in[8];
  const float* W_ih     = (const float*)d_in[9];
  const float* W_hh     = (const float*)d_in[10];
  const float* b_ih     = (const float*)d_in[11];
  const float* b_hh     = (const float*)d_in[12];
  const float* W_out    = (const float*)d_in[13];
  const float* b_out    = (const float*)d_in[14];

  float* ws    = (float*)d_ws;
  float* fmean = ws;                             // 32768
  float* ctx   = fmean + B_ * VD_;               // 32768
  float* hbuf  = ctx + B_ * VD_;                 // 32768 (fp32 h0)
  float* cbuf  = hbuf + B_ * HD_;                // 32768 (c0)
  float* gctx  = cbuf + B_ * HD_;                // 131072
  float* svg   = gctx + (size_t)B_ * G4_;        // 12544 -> pad 12608
  float* gpre  = svg + 12608;                    // 2,621,440
  int*   bar   = (int*)(gpre + (size_t)T_ * B_ * G4_);                       // 512 ints (32 flags, 64B stride)
  unsigned short* wout_bf = (unsigned short*)(bar + 512);                    // 5,120,000
  unsigned short* wihe_bf = wout_bf + (size_t)V_ * HD_;                      // 1,048,576
  unsigned short* whh_bf  = wihe_bf + (size_t)G4_ * ED_;                     // 1,048,576
  unsigned short* emb_bf  = whh_bf + (size_t)G4_ * HD_;                      // 655,360
  unsigned short* h0_bf   = emb_bf + (size_t)T_ * B_ * ED_;                  // 32,768
  unsigned short* hall_bf = h0_bf + (size_t)B_ * HD_;                        // 655,360
  // total ~28.8 MB

  float* out1   = (float*)d_out;                     // log_softmax [T,B,V]
  float* logits = out1 + (size_t)T_ * B_ * V_;       // softmax slot = scratch

  hipMemsetAsync(bar, 0, 2048, stream);

  k_prep<<<7944, 256, 0, stream>>>(W_out, W_ih, W_hh, embed, captions,
                                   features, W_av,
                                   wout_bf, wihe_bf, whh_bf, emb_bf, svg);
  k_attn2<<<dim3(B_, 4), 256, 0, stream>>>(features, svg, fmean, ctx);
  k_small<<<48, 256, 0, stream>>>(fmean, ctx, W_init_h, W_init_c, W_ih,
                                  b_ih, b_hh, hbuf, cbuf, gctx, h0_bf);

  // gpre[t*64+b, :] = emb_bf @ wihe_bf^T + gctx[b, :]  (gctx includes biases)
  k_gemm_mfma<<<dim3(G4_ / 128, (T_ * B_) / 128), 256, 0, stream>>>(
      emb_bf, wihe_bf, nullptr, gctx, G4_, gpre, T_ * B_, G4_, ED_);

  // all 20 LSTM steps, ONE launch (32-block persistent, flag barrier)
  k_lstm_mfma<<<LSTM_NBLK, 256, 0, stream>>>(
      whh_bf, gpre, h0_bf, cbuf, hall_bf, bar);

  // logits = hall @ W_out^T + b_out  (bf16 MFMA, fp32 accumulate)
  k_gemm_mfma<<<dim3((V_ + 127) / 128, (T_ * B_) / 128), 256, 0, stream>>>(
      hall_bf, wout_bf, b_out, nullptr, 0, logits, T_ * B_, V_, HD_);

  k_softmax<<<T_ * B_, 256, 0, stream>>>(logits, out1);
}

// Round 3
// 442.397 us; speedup vs baseline: 1.3980x; 1.0615x over previous
//
#include <hip/hip_runtime.h>
#include <math.h>

#define B_   64
#define N_   196
#define VD_  512
#define ED_  512
#define HD_  512
#define V_   10000
#define T_   20
#define G4_  2048   // 4*HD
#define LSTM_NBLK 32
#define WNW   224   // logits worker blocks
#define NITEM 790   // (1280/128) * ceil(10000/128) = 10*79 logits tiles

typedef __attribute__((ext_vector_type(8))) short bf16x8;
typedef __attribute__((ext_vector_type(4))) float f32x4;

static __device__ __forceinline__ float sigmoidf_(float x) {
  return 1.f / (1.f + __expf(-x));
}

static __device__ __forceinline__ float tanh_fast(float x) {
  // 1 - 2/(e^{2x}+1); saturates correctly at +/-1, error << bf16 rounding
  float e = __expf(2.f * x);
  return 1.f - 2.f / (e + 1.f);
}

static __device__ __forceinline__ unsigned short f2bf_(float x) {
  unsigned u = __float_as_uint(x);
  unsigned r = (u + 0x7FFFu + ((u >> 16) & 1u)) >> 16;   // RNE
  return (unsigned short)r;
}

// ---------------------------------------------------------------------------
// k_prep: all fp32->bf16 casts + embedding gather-cast + attention logits,
// one launch (independent segments by blockIdx).
// ---------------------------------------------------------------------------
__global__ void k_prep(const float* __restrict__ W_out,
                       const float* __restrict__ W_ih,
                       const float* __restrict__ W_hh,
                       const float* __restrict__ embed,
                       const int* __restrict__ caps,
                       const float* __restrict__ feat,
                       const float* __restrict__ W_av,
                       unsigned short* __restrict__ wout_bf,
                       unsigned short* __restrict__ wihe_bf,
                       unsigned short* __restrict__ whh_bf,
                       unsigned short* __restrict__ emb_bf,
                       float* __restrict__ svg) {
  int bx = blockIdx.x, tid = threadIdx.x;
  if (bx >= 7688) {   // attn1 segment
    int r = bx - 7688;
    int b = r >> 2, q = r & 3;
    int lane = tid & 63, w = tid >> 6;
    const float* fb = feat + (size_t)b * (N_ * VD_);
    float4 wv0 = *(const float4*)(W_av + lane * 8);
    float4 wv1 = *(const float4*)(W_av + lane * 8 + 4);
    int nbase = q * 49;
    for (int n = nbase + w; n < nbase + 49; n += 4) {
      const float* fp = fb + n * VD_ + lane * 8;
      float4 f0 = *(const float4*)fp;
      float4 f1 = *(const float4*)(fp + 4);
      float p = f0.x * wv0.x + f0.y * wv0.y + f0.z * wv0.z + f0.w * wv0.w
              + f1.x * wv1.x + f1.y * wv1.y + f1.z * wv1.z + f1.w * wv1.w;
#pragma unroll
      for (int off = 32; off > 0; off >>= 1) p += __shfl_down(p, off, 64);
      if (lane == 0) svg[b * N_ + n] = p;
    }
    return;
  }
  float4 v; unsigned short* dst; int i;
  if (bx < 5000) {
    i = bx * 256 + tid;
    v = ((const float4*)W_out)[i];
    dst = wout_bf;
  } else if (bx < 6024) {
    i = (bx - 5000) * 256 + tid;
    int j = i >> 7, kk = (i & 127) << 2;
    v = *(const float4*)(W_ih + (size_t)j * (VD_ + ED_) + VD_ + kk);
    dst = wihe_bf;
  } else if (bx < 6664) {
    i = (bx - 6024) * 256 + tid;
    int row = i >> 7;                          // t*64+b
    int b = row & 63, t = row >> 6;
    v = *(const float4*)(embed + (size_t)caps[b * T_ + t] * ED_ + ((i & 127) << 2));
    dst = emb_bf;
  } else {
    i = (bx - 6664) * 256 + tid;
    v = ((const float4*)W_hh)[i];
    dst = whh_bf;
  }
  ushort4 o;
  o.x = f2bf_(v.x); o.y = f2bf_(v.y); o.z = f2bf_(v.z); o.w = f2bf_(v.w);
  ((ushort4*)dst)[i] = o;
}

// ---------------------------------------------------------------------------
// k_attn2: softmax(svg[b]) -> weights; ctx + fmean for a 128-dim chunk.
// ---------------------------------------------------------------------------
__global__ void k_attn2(const float* __restrict__ feat,
                        const float* __restrict__ svg,
                        float* __restrict__ fmean,
                        float* __restrict__ ctx) {
  __shared__ float sa[200];
  __shared__ float red[8];
  __shared__ float pc[2][128];
  __shared__ float pf[2][128];
  int b = blockIdx.x, q = blockIdx.y;
  int tid = threadIdx.x, lane = tid & 63, w = tid >> 6;
  const float* fb = feat + (size_t)b * (N_ * VD_);

  float v = (tid < N_) ? svg[b * N_ + tid] : -1e30f;
  float m = v;
#pragma unroll
  for (int off = 32; off > 0; off >>= 1) m = fmaxf(m, __shfl_down(m, off, 64));
  if (lane == 0) red[w] = m;
  __syncthreads();
  m = fmaxf(fmaxf(red[0], red[1]), fmaxf(red[2], red[3]));

  float e = (tid < N_) ? __expf(v - m) : 0.f;
  float s = e;
#pragma unroll
  for (int off = 32; off > 0; off >>= 1) s += __shfl_down(s, off, 64);
  if (lane == 0) red[4 + w] = s;
  __syncthreads();
  float inv = 1.f / (red[4] + red[5] + red[6] + red[7]);
  if (tid < N_) sa[tid] = e * inv;
  __syncthreads();

  int d = q * 128 + (tid & 127);
  int nh = tid >> 7;
  float c = 0.f, fs = 0.f;
  for (int n = nh; n < N_; n += 2) {
    float f = fb[n * VD_ + d];
    c += sa[n] * f;
    fs += f;
  }
  pc[nh][tid & 127] = c;
  pf[nh][tid & 127] = fs;
  __syncthreads();
  if (tid < 128) {
    ctx[b * VD_ + q * 128 + tid] = pc[0][tid] + pc[1][tid];
    fmean[b * VD_ + q * 128 + tid] = (pf[0][tid] + pf[1][tid]) * (1.f / N_);
  }
}

// ---------------------------------------------------------------------------
// k_small: three M=64 fp32 GEMMs in one launch (48 blocks).
// ---------------------------------------------------------------------------
#define BK 16
__global__ __launch_bounds__(256) void k_small(
    const float* __restrict__ fmean, const float* __restrict__ ctx,
    const float* __restrict__ W_init_h, const float* __restrict__ W_init_c,
    const float* __restrict__ W_ih,
    const float* __restrict__ b_ih, const float* __restrict__ b_hh,
    float* __restrict__ hbuf, float* __restrict__ cbuf, float* __restrict__ gctx,
    unsigned short* __restrict__ h0_bf) {
  const float* A; const float* Bw; float* C;
  int ldb, ldc, n0;
  const float* bias1 = nullptr; const float* bias2 = nullptr;
  unsigned short* hb = nullptr;
  int bx = blockIdx.x;
  if (bx < 8)       { A = fmean; Bw = W_init_h; C = hbuf; ldb = VD_; ldc = HD_; n0 = bx * 64; hb = h0_bf; }
  else if (bx < 16) { A = fmean; Bw = W_init_c; C = cbuf; ldb = VD_; ldc = HD_; n0 = (bx - 8) * 64; }
  else { A = ctx; Bw = W_ih; C = gctx; ldb = VD_ + ED_; ldc = G4_; n0 = (bx - 16) * 64;
         bias1 = b_ih; bias2 = b_hh; }

  __shared__ float As[BK][64];
  __shared__ float Bs[BK][64];
  int tid = threadIdx.x;
  int tm = tid & 15, tn = tid >> 4;
  int sr = tid >> 2, sk = (tid & 3) * 4;
  const float* arow = A + (size_t)sr * VD_;
  const float* brow = Bw + (size_t)(n0 + sr) * ldb;
  float acc[4][4] = {};

  for (int k0 = 0; k0 < VD_; k0 += BK) {
    float4 av = *(const float4*)(arow + k0 + sk);
    float4 bv = *(const float4*)(brow + k0 + sk);
    __syncthreads();
    As[sk + 0][sr] = av.x; As[sk + 1][sr] = av.y;
    As[sk + 2][sr] = av.z; As[sk + 3][sr] = av.w;
    Bs[sk + 0][sr] = bv.x; Bs[sk + 1][sr] = bv.y;
    Bs[sk + 2][sr] = bv.z; Bs[sk + 3][sr] = bv.w;
    __syncthreads();
#pragma unroll
    for (int kk = 0; kk < BK; ++kk) {
      float4 a4 = *(const float4*)&As[kk][tm * 4];
      float4 b4 = *(const float4*)&Bs[kk][tn * 4];
      acc[0][0] += a4.x * b4.x; acc[0][1] += a4.x * b4.y; acc[0][2] += a4.x * b4.z; acc[0][3] += a4.x * b4.w;
      acc[1][0] += a4.y * b4.x; acc[1][1] += a4.y * b4.y; acc[1][2] += a4.y * b4.z; acc[1][3] += a4.y * b4.w;
      acc[2][0] += a4.z * b4.x; acc[2][1] += a4.z * b4.y; acc[2][2] += a4.z * b4.z; acc[2][3] += a4.z * b4.w;
      acc[3][0] += a4.w * b4.x; acc[3][1] += a4.w * b4.y; acc[3][2] += a4.w * b4.z; acc[3][3] += a4.w * b4.w;
    }
  }
#pragma unroll
  for (int j = 0; j < 4; ++j) {
    int n = n0 + tn * 4 + j;
    float bb = (bias1 ? bias1[n] + bias2[n] : 0.f);
#pragma unroll
    for (int i = 0; i < 4; ++i) {
      int mm = tm * 4 + i;
      float val = acc[i][j] + bb;
      C[(size_t)mm * ldc + n] = val;
      if (hb) hb[(size_t)mm * HD_ + n] = f2bf_(val);
    }
  }
}

// ---------------------------------------------------------------------------
// Staged bf16 MFMA GEMM: C[M,N] = A[M,K]@Bw[N,K]^T (+bias[n]) (+radd[m&63,n]).
// 128x128 block tile, BK=32, LDS-staged, 4 waves 2x2. (Used for gpre only.)
// ---------------------------------------------------------------------------
__global__ __launch_bounds__(256) void k_gemm_mfma(
    const unsigned short* __restrict__ A,
    const unsigned short* __restrict__ Bw,
    const float* __restrict__ bias,
    const float* __restrict__ radd, int ldr,
    float* __restrict__ C, int M, int Nn, int K) {
  __shared__ unsigned short As[128][32];
  __shared__ unsigned short Bs[128][32];
  int tid = threadIdx.x;
  int wave = tid >> 6, lane = tid & 63;
  int wm = wave & 1, wn = wave >> 1;
  int m0 = blockIdx.y * 128, n0 = blockIdx.x * 128;
  int l15 = lane & 15, quad = lane >> 4;
  int sr = tid >> 1, skq = (tid & 1) * 16;
  const unsigned short* ga = A + (size_t)(m0 + sr) * K + skq;
  int bn = n0 + sr; if (bn >= Nn) bn = Nn - 1;
  const unsigned short* gb = Bw + (size_t)bn * K + skq;

  f32x4 acc[4][4];
#pragma unroll
  for (int i = 0; i < 4; ++i)
#pragma unroll
    for (int j = 0; j < 4; ++j) acc[i][j] = (f32x4){0.f, 0.f, 0.f, 0.f};

  for (int k0 = 0; k0 < K; k0 += 32) {
    bf16x8 a0 = *(const bf16x8*)(ga + k0);
    bf16x8 a1 = *(const bf16x8*)(ga + k0 + 8);
    bf16x8 b0 = *(const bf16x8*)(gb + k0);
    bf16x8 b1 = *(const bf16x8*)(gb + k0 + 8);
    __syncthreads();
    *(bf16x8*)&As[sr][skq] = a0; *(bf16x8*)&As[sr][skq + 8] = a1;
    *(bf16x8*)&Bs[sr][skq] = b0; *(bf16x8*)&Bs[sr][skq + 8] = b1;
    __syncthreads();
    bf16x8 af[4], bfr[4];
#pragma unroll
    for (int mt = 0; mt < 4; ++mt)
      af[mt] = *(const bf16x8*)&As[wm * 64 + mt * 16 + l15][quad * 8];
#pragma unroll
    for (int nt = 0; nt < 4; ++nt)
      bfr[nt] = *(const bf16x8*)&Bs[wn * 64 + nt * 16 + l15][quad * 8];
#pragma unroll
    for (int mt = 0; mt < 4; ++mt)
#pragma unroll
      for (int nt = 0; nt < 4; ++nt)
        acc[mt][nt] = __builtin_amdgcn_mfma_f32_16x16x32_bf16(af[mt], bfr[nt], acc[mt][nt], 0, 0, 0);
  }

#pragma unroll
  for (int nt = 0; nt < 4; ++nt) {
    int n = n0 + wn * 64 + nt * 16 + l15;
    if (n < Nn) {
      float bb = bias ? bias[n] : 0.f;
#pragma unroll
      for (int mt = 0; mt < 4; ++mt) {
        int mbase = m0 + wm * 64 + mt * 16 + quad * 4;
#pragma unroll
        for (int r = 0; r < 4; ++r) {
          int mg = mbase + r;
          float ra = radd ? radd[(size_t)(mg & 63) * ldr + n] : 0.f;
          C[(size_t)mg * Nn + n] = acc[mt][nt][r] + bb + ra;
        }
      }
    }
  }
}

// ---------------------------------------------------------------------------
// Mega-kernel: 32 LSTM blocks (v3 recurrence, unchanged) + WNW logits-worker
// blocks, ONE launch. Workers consume hall[t] as the LSTM publishes it
// (gated on the per-block step flags), computing logits = hall@W_out^T+b_out
// on the 224 otherwise-idle CUs, fully hidden under the recurrence. The
// standalone logits GEMM launch disappears. No deadlock: workers wait on
// LSTM flags only; LSTM blocks (0..31, dispatched first, co-resident) wait
// on nothing from workers. LSTM adds one final flag store (t=20) so workers
// can consume hall[19].
// ---------------------------------------------------------------------------
__global__ __launch_bounds__(256, 1) void k_lstm_logits(
    const unsigned short* __restrict__ whh_bf,   // [2048][512] bf16
    const float* __restrict__ gpre,              // [T*64][2048]
    const unsigned short* __restrict__ h0_bf,    // [64][512] bf16
    const float* __restrict__ c0,                // [64][512] fp32
    unsigned short* __restrict__ hall_bf,        // [T][64][512] bf16
    int* __restrict__ bar,                       // [32*16] flags, 64B stride
    const unsigned short* __restrict__ wout_bf,  // [10000][512] bf16
    const float* __restrict__ b_out,             // [10000]
    float* __restrict__ logits) {                // [T*64][10000] fp32
  __shared__ unsigned short smem[64 * 512];      // lstm: whh 64KB; worker: As+Bs 16KB
  int bx = blockIdx.x;
  int tid = threadIdx.x;
  int wave = tid >> 6, lane = tid & 63;
  int l15 = lane & 15, quad = lane >> 4;

  if (bx < LSTM_NBLK) {
    // ======================= LSTM path (v3) ================================
    int w = wave;
    int n0 = bx * 16;

    // stage whh slice into LDS, one-time, XOR-swizzled
    for (int idx = tid; idx < 4096; idx += 256) {
      int r = idx >> 6, gg = idx & 63;
      int gate = r >> 4, l = r & 15;
      bf16x8 v = *(const bf16x8*)(whh_bf +
          (size_t)(gate * HD_ + n0 + l) * HD_ + gg * 8);
      *(bf16x8*)&smem[r * 512 + (gg ^ (r & 7)) * 8] = v;
    }

    int brow = w * 16 + quad * 4;

    float c_reg[4];
#pragma unroll
    for (int r = 0; r < 4; ++r)
      c_reg[r] = c0[(size_t)(brow + r) * HD_ + n0 + l15];

    float gr[16];
#pragma unroll
    for (int g = 0; g < 4; ++g)
#pragma unroll
      for (int r = 0; r < 4; ++r)
        gr[g * 4 + r] = gpre[(size_t)(brow + r) * G4_ + g * HD_ + n0 + l15];

    __syncthreads();   // whh ready

    for (int t = 0; t < T_; ++t) {
      const unsigned short* h_in =
          (t == 0) ? h0_bf : (hall_bf + (size_t)(t - 1) * B_ * HD_);
      const unsigned short* ar = h_in + (size_t)(w * 16 + l15) * HD_ + quad * 8;

      bf16x8 a[16];
#pragma unroll
      for (int ki = 0; ki < 16; ++ki)
        asm volatile("global_load_dwordx4 %0, %1, off sc0 sc1"
                     : "=v"(a[ki]) : "v"(ar + ki * 32) : "memory");
      asm volatile("s_waitcnt vmcnt(0)" ::: "memory");
      __builtin_amdgcn_sched_barrier(0);

      f32x4 acc[4];
#pragma unroll
      for (int i = 0; i < 4; ++i) acc[i] = (f32x4){0.f, 0.f, 0.f, 0.f};

#pragma unroll
      for (int ki = 0; ki < 16; ++ki) {
        int rb = l15 * 512 + (((ki * 4 + quad) ^ (l15 & 7)) << 3);
#pragma unroll
        for (int nt = 0; nt < 4; ++nt) {
          bf16x8 b = *(const bf16x8*)&smem[nt * 16 * 512 + rb];
          acc[nt] = __builtin_amdgcn_mfma_f32_16x16x32_bf16(a[ki], b, acc[nt], 0, 0, 0);
        }
      }

      unsigned short* hout = hall_bf + (size_t)t * B_ * HD_;
#pragma unroll
      for (int r = 0; r < 4; ++r) {
        float gi = acc[0][r] + gr[0 + r];
        float gf = acc[1][r] + gr[4 + r];
        float gg = acc[2][r] + gr[8 + r];
        float go = acc[3][r] + gr[12 + r];
        float cn = sigmoidf_(gf) * c_reg[r] + sigmoidf_(gi) * tanh_fast(gg);
        c_reg[r] = cn;
        unsigned hv = f2bf_(sigmoidf_(go) * tanh_fast(cn));
        unsigned short* sp = hout + (size_t)(brow + r) * HD_ + n0 + l15;
        asm volatile("global_store_short %0, %1, off sc0 sc1"
                     :: "v"(sp), "v"(hv) : "memory");
      }

      asm volatile("s_waitcnt vmcnt(0)" ::: "memory");  // h at coherence pt
      __syncthreads();                                  // all waves drained
      if (tid == 0) {
        int* fp = bar + bx * 16;
        int fv = t + 1;
        asm volatile("global_store_dword %0, %1, off sc0 sc1"
                     :: "v"(fp), "v"(fv) : "memory");
      }
      if (t < T_ - 1) {
        // prefetch gpre for t+1 — overlaps the barrier wait
        const float* gpt = gpre + (size_t)(t + 1) * B_ * G4_;
#pragma unroll
        for (int g = 0; g < 4; ++g)
#pragma unroll
          for (int r = 0; r < 4; ++r)
            gr[g * 4 + r] = gpt[(size_t)(brow + r) * G4_ + g * HD_ + n0 + l15];
        if (tid < 64) {   // wave 0: lanes 0..31 watch one flag each
          int* fp = bar + (tid & 31) * 16;
          while (true) {
            int v = __hip_atomic_load(fp, __ATOMIC_RELAXED,
                                      __HIP_MEMORY_SCOPE_AGENT);
            if (__all(v >= t + 1)) break;
            __builtin_amdgcn_s_sleep(1);
          }
        }
        __syncthreads();
      }
    }
  } else {
    // ===================== logits worker path ==============================
    // item q -> 128x128 tile of logits[1280][10000]: rows m0=128*(q/79)
    // (covers timesteps m0/64, m0/64+1), cols n0=128*(q%79). Requires
    // hall rows < m0+128 published: all 32 flags >= m0/64 + 2.
    int wq = bx - LSTM_NBLK;
    unsigned short (*As)[32] = (unsigned short (*)[32])smem;
    unsigned short (*Bs)[32] = (unsigned short (*)[32])(smem + 128 * 32);
    int wm = wave & 1, wn = wave >> 1;
    int sr = tid >> 1, skq = (tid & 1) * 16;

    for (int q = wq; q < NITEM; q += WNW) {
      int mt_ = q / 79, vt = q - mt_ * 79;
      int m0 = mt_ * 128, n0 = vt * 128;
      int tneed = (m0 >> 6) + 2;

      if (tid < 64) {
        const int* fp = bar + (tid & 31) * 16;
        while (true) {
          int v = __hip_atomic_load(fp, __ATOMIC_RELAXED,
                                    __HIP_MEMORY_SCOPE_AGENT);
          if (__all(v >= tneed)) break;
          __builtin_amdgcn_s_sleep(16);
        }
      }
      __syncthreads();

      const unsigned short* ga = hall_bf + (size_t)(m0 + sr) * HD_ + skq;
      int bn = n0 + sr; if (bn >= V_) bn = V_ - 1;
      const unsigned short* gb = wout_bf + (size_t)bn * HD_ + skq;

      f32x4 acc[4][4];
#pragma unroll
      for (int i = 0; i < 4; ++i)
#pragma unroll
        for (int j = 0; j < 4; ++j) acc[i][j] = (f32x4){0.f, 0.f, 0.f, 0.f};

      for (int k0 = 0; k0 < HD_; k0 += 32) {
        bf16x8 a0, a1, b0v, b1v;
        // hall written sc0sc1 by LSTM -> read from coherence point
        asm volatile("global_load_dwordx4 %0, %1, off sc0 sc1"
                     : "=v"(a0) : "v"(ga + k0) : "memory");
        asm volatile("global_load_dwordx4 %0, %1, off sc0 sc1"
                     : "=v"(a1) : "v"(ga + k0 + 8) : "memory");
        b0v = *(const bf16x8*)(gb + k0);
        b1v = *(const bf16x8*)(gb + k0 + 8);
        asm volatile("s_waitcnt vmcnt(0)" ::: "memory");
        __syncthreads();
        *(bf16x8*)&As[sr][skq] = a0; *(bf16x8*)&As[sr][skq + 8] = a1;
        *(bf16x8*)&Bs[sr][skq] = b0v; *(bf16x8*)&Bs[sr][skq + 8] = b1v;
        __syncthreads();
        bf16x8 af[4], bfr[4];
#pragma unroll
        for (int mt = 0; mt < 4; ++mt)
          af[mt] = *(const bf16x8*)&As[wm * 64 + mt * 16 + l15][quad * 8];
#pragma unroll
        for (int nt = 0; nt < 4; ++nt)
          bfr[nt] = *(const bf16x8*)&Bs[wn * 64 + nt * 16 + l15][quad * 8];
#pragma unroll
        for (int mt = 0; mt < 4; ++mt)
#pragma unroll
          for (int nt = 0; nt < 4; ++nt)
            acc[mt][nt] = __builtin_amdgcn_mfma_f32_16x16x32_bf16(
                af[mt], bfr[nt], acc[mt][nt], 0, 0, 0);
      }

#pragma unroll
      for (int nt = 0; nt < 4; ++nt) {
        int n = n0 + wn * 64 + nt * 16 + l15;
        if (n < V_) {
          float bb = b_out[n];
#pragma unroll
          for (int mt = 0; mt < 4; ++mt) {
            int mbase = m0 + wm * 64 + mt * 16 + quad * 4;
#pragma unroll
            for (int r = 0; r < 4; ++r) {
              int mg = mbase + r;
              logits[(size_t)mg * V_ + n] = acc[mt][nt][r] + bb;
            }
          }
        }
      }
    }
  }
}

// ---------------------------------------------------------------------------
// Fused log_softmax + softmax per row of logits [1280][10000].
// ---------------------------------------------------------------------------
__global__ void k_softmax(float* __restrict__ logits, float* __restrict__ out1) {
  __shared__ float red[8];
  int row = blockIdx.x, tid = threadIdx.x;
  int lane = tid & 63, wid = tid >> 6;
  float* lr = logits + (size_t)row * V_;
  float* o1 = out1 + (size_t)row * V_;
  const int NV4 = V_ / 4;  // 2500

  float m = -1e30f;
  for (int i = tid; i < NV4; i += 256) {
    float4 v = ((const float4*)lr)[i];
    m = fmaxf(m, fmaxf(fmaxf(v.x, v.y), fmaxf(v.z, v.w)));
  }
#pragma unroll
  for (int off = 32; off > 0; off >>= 1) m = fmaxf(m, __shfl_down(m, off, 64));
  if (lane == 0) red[4 + wid] = m;
  __syncthreads();
  m = fmaxf(fmaxf(red[4], red[5]), fmaxf(red[6], red[7]));

  float s = 0.f;
  for (int i = tid; i < NV4; i += 256) {
    float4 v = ((const float4*)lr)[i];
    s += __expf(v.x - m) + __expf(v.y - m) + __expf(v.z - m) + __expf(v.w - m);
  }
#pragma unroll
  for (int off = 32; off > 0; off >>= 1) s += __shfl_down(s, off, 64);
  if (lane == 0) red[wid] = s;
  __syncthreads();
  s = red[0] + red[1] + red[2] + red[3];
  float ls = __logf(s), inv = 1.f / s;

  for (int i = tid; i < NV4; i += 256) {
    float4 v = ((const float4*)lr)[i];
    float4 a, bb;
    a.x = v.x - m - ls; a.y = v.y - m - ls; a.z = v.z - m - ls; a.w = v.w - m - ls;
    bb.x = __expf(v.x - m) * inv; bb.y = __expf(v.y - m) * inv;
    bb.z = __expf(v.z - m) * inv; bb.w = __expf(v.w - m) * inv;
    ((float4*)o1)[i] = a;
    ((float4*)lr)[i] = bb;
  }
}

// ---------------------------------------------------------------------------
extern "C" void kernel_launch(void* const* d_in, const int* in_sizes, int n_in,
                              void* d_out, int out_size, void* d_ws, size_t ws_size,
                              hipStream_t stream) {
  const float* features = (const float*)d_in[0];
  const int*   captions = (const int*)d_in[1];
  const float* W_init_h = (const float*)d_in[2];
  const float* W_init_c = (const float*)d_in[3];
  const float* W_av     = (const float*)d_in[4];
  // d_in[5] b_av, d_in[6] W_ah, d_in[7] b_ah: cancel inside softmax over n.
  const float* embed    = (const float*)d_in[8];
  const float* W_ih     = (const float*)d_in[9];
  const float* W_hh     = (const float*)d_in[10];
  const float* b_ih     = (const float*)d_in[11];
  const float* b_hh     = (const float*)d_in[12];
  const float* W_out    = (const float*)d_in[13];
  const float* b_out    = (const float*)d_in[14];

  float* ws    = (float*)d_ws;
  float* fmean = ws;                             // 32768
  float* ctx   = fmean + B_ * VD_;               // 32768
  float* hbuf  = ctx + B_ * VD_;                 // 32768 (fp32 h0)
  float* cbuf  = hbuf + B_ * HD_;                // 32768 (c0)
  float* gctx  = cbuf + B_ * HD_;                // 131072
  float* svg   = gctx + (size_t)B_ * G4_;        // 12544 -> pad 12608
  float* gpre  = svg + 12608;                    // 2,621,440
  int*   bar   = (int*)(gpre + (size_t)T_ * B_ * G4_);                       // 512 ints (32 flags, 64B stride)
  unsigned short* wout_bf = (unsigned short*)(bar + 512);                    // 5,120,000
  unsigned short* wihe_bf = wout_bf + (size_t)V_ * HD_;                      // 1,048,576
  unsigned short* whh_bf  = wihe_bf + (size_t)G4_ * ED_;                     // 1,048,576
  unsigned short* emb_bf  = whh_bf + (size_t)G4_ * HD_;                      // 655,360
  unsigned short* h0_bf   = emb_bf + (size_t)T_ * B_ * ED_;                  // 32,768
  unsigned short* hall_bf = h0_bf + (size_t)B_ * HD_;                        // 655,360
  // total ~28.8 MB

  float* out1   = (float*)d_out;                     // log_softmax [T,B,V]
  float* logits = out1 + (size_t)T_ * B_ * V_;       // softmax slot = scratch

  hipMemsetAsync(bar, 0, 2048, stream);

  k_prep<<<7944, 256, 0, stream>>>(W_out, W_ih, W_hh, embed, captions,
                                   features, W_av,
                                   wout_bf, wihe_bf, whh_bf, emb_bf, svg);
  k_attn2<<<dim3(B_, 4), 256, 0, stream>>>(features, svg, fmean, ctx);
  k_small<<<48, 256, 0, stream>>>(fmean, ctx, W_init_h, W_init_c, W_ih,
                                  b_ih, b_hh, hbuf, cbuf, gctx, h0_bf);

  // gpre[t*64+b, :] = emb_bf @ wihe_bf^T + gctx[b, :]  (gctx includes biases)
  k_gemm_mfma<<<dim3(G4_ / 128, (T_ * B_) / 128), 256, 0, stream>>>(
      emb_bf, wihe_bf, nullptr, gctx, G4_, gpre, T_ * B_, G4_, ED_);

  // LSTM (32 persistent blocks) + logits GEMM (224 flag-gated workers),
  // ONE launch: logits compute hides under the recurrence's exchange idle.
  k_lstm_logits<<<LSTM_NBLK + WNW, 256, 0, stream>>>(
      whh_bf, gpre, h0_bf, cbuf, hall_bf, bar, wout_bf, b_out, logits);

  k_softmax<<<T_ * B_, 256, 0, stream>>>(logits, out1);
}

// Round 6
// 428.846 us; speedup vs baseline: 1.4422x; 1.0316x over previous
//
#include <hip/hip_runtime.h>
#include <math.h>

#define B_   64
#define N_   196
#define VD_  512
#define ED_  512
#define HD_  512
#define V_   10000
#define T_   20
#define G4_  2048   // 4*HD
#define LSTM_NBLK 32
#define WNW   224   // logits worker blocks
#define NITEM 790   // (1280/128) * ceil(10000/128) = 10*79 logits tiles

typedef __attribute__((ext_vector_type(8))) short bf16x8;
typedef __attribute__((ext_vector_type(4))) float f32x4;

static __device__ __forceinline__ float sigmoidf_(float x) {
  return 1.f / (1.f + __expf(-x));
}

static __device__ __forceinline__ float tanh_fast(float x) {
  // 1 - 2/(e^{2x}+1); saturates correctly at +/-1, error << bf16 rounding
  float e = __expf(2.f * x);
  return 1.f - 2.f / (e + 1.f);
}

static __device__ __forceinline__ unsigned short f2bf_(float x) {
  unsigned u = __float_as_uint(x);
  unsigned r = (u + 0x7FFFu + ((u >> 16) & 1u)) >> 16;   // RNE
  return (unsigned short)r;
}

// ---------------------------------------------------------------------------
// k_prep: all fp32->bf16 casts + embedding gather-cast + attention logits,
// one launch (independent segments by blockIdx).
// ---------------------------------------------------------------------------
__global__ void k_prep(const float* __restrict__ W_out,
                       const float* __restrict__ W_ih,
                       const float* __restrict__ W_hh,
                       const float* __restrict__ embed,
                       const int* __restrict__ caps,
                       const float* __restrict__ feat,
                       const float* __restrict__ W_av,
                       unsigned short* __restrict__ wout_bf,
                       unsigned short* __restrict__ wihe_bf,
                       unsigned short* __restrict__ whh_bf,
                       unsigned short* __restrict__ emb_bf,
                       float* __restrict__ svg) {
  int bx = blockIdx.x, tid = threadIdx.x;
  if (bx >= 7688) {   // attn1 segment
    int r = bx - 7688;
    int b = r >> 2, q = r & 3;
    int lane = tid & 63, w = tid >> 6;
    const float* fb = feat + (size_t)b * (N_ * VD_);
    float4 wv0 = *(const float4*)(W_av + lane * 8);
    float4 wv1 = *(const float4*)(W_av + lane * 8 + 4);
    int nbase = q * 49;
    for (int n = nbase + w; n < nbase + 49; n += 4) {
      const float* fp = fb + n * VD_ + lane * 8;
      float4 f0 = *(const float4*)fp;
      float4 f1 = *(const float4*)(fp + 4);
      float p = f0.x * wv0.x + f0.y * wv0.y + f0.z * wv0.z + f0.w * wv0.w
              + f1.x * wv1.x + f1.y * wv1.y + f1.z * wv1.z + f1.w * wv1.w;
#pragma unroll
      for (int off = 32; off > 0; off >>= 1) p += __shfl_down(p, off, 64);
      if (lane == 0) svg[b * N_ + n] = p;
    }
    return;
  }
  float4 v; unsigned short* dst; int i;
  if (bx < 5000) {
    i = bx * 256 + tid;
    v = ((const float4*)W_out)[i];
    dst = wout_bf;
  } else if (bx < 6024) {
    i = (bx - 5000) * 256 + tid;
    int j = i >> 7, kk = (i & 127) << 2;
    v = *(const float4*)(W_ih + (size_t)j * (VD_ + ED_) + VD_ + kk);
    dst = wihe_bf;
  } else if (bx < 6664) {
    i = (bx - 6024) * 256 + tid;
    int row = i >> 7;                          // t*64+b
    int b = row & 63, t = row >> 6;
    v = *(const float4*)(embed + (size_t)caps[b * T_ + t] * ED_ + ((i & 127) << 2));
    dst = emb_bf;
  } else {
    i = (bx - 6664) * 256 + tid;
    v = ((const float4*)W_hh)[i];
    dst = whh_bf;
  }
  ushort4 o;
  o.x = f2bf_(v.x); o.y = f2bf_(v.y); o.z = f2bf_(v.z); o.w = f2bf_(v.w);
  ((ushort4*)dst)[i] = o;
}

// ---------------------------------------------------------------------------
// k_attn2: softmax(svg[b]) -> weights; ctx + fmean for a 128-dim chunk.
// ---------------------------------------------------------------------------
__global__ void k_attn2(const float* __restrict__ feat,
                        const float* __restrict__ svg,
                        float* __restrict__ fmean,
                        float* __restrict__ ctx) {
  __shared__ float sa[200];
  __shared__ float red[8];
  __shared__ float pc[2][128];
  __shared__ float pf[2][128];
  int b = blockIdx.x, q = blockIdx.y;
  int tid = threadIdx.x, lane = tid & 63, w = tid >> 6;
  const float* fb = feat + (size_t)b * (N_ * VD_);

  float v = (tid < N_) ? svg[b * N_ + tid] : -1e30f;
  float m = v;
#pragma unroll
  for (int off = 32; off > 0; off >>= 1) m = fmaxf(m, __shfl_down(m, off, 64));
  if (lane == 0) red[w] = m;
  __syncthreads();
  m = fmaxf(fmaxf(red[0], red[1]), fmaxf(red[2], red[3]));

  float e = (tid < N_) ? __expf(v - m) : 0.f;
  float s = e;
#pragma unroll
  for (int off = 32; off > 0; off >>= 1) s += __shfl_down(s, off, 64);
  if (lane == 0) red[4 + w] = s;
  __syncthreads();
  float inv = 1.f / (red[4] + red[5] + red[6] + red[7]);
  if (tid < N_) sa[tid] = e * inv;
  __syncthreads();

  int d = q * 128 + (tid & 127);
  int nh = tid >> 7;
  float c = 0.f, fs = 0.f;
  for (int n = nh; n < N_; n += 2) {
    float f = fb[n * VD_ + d];
    c += sa[n] * f;
    fs += f;
  }
  pc[nh][tid & 127] = c;
  pf[nh][tid & 127] = fs;
  __syncthreads();
  if (tid < 128) {
    ctx[b * VD_ + q * 128 + tid] = pc[0][tid] + pc[1][tid];
    fmean[b * VD_ + q * 128 + tid] = (pf[0][tid] + pf[1][tid]) * (1.f / N_);
  }
}

// ---------------------------------------------------------------------------
// k_small: three M=64 fp32 GEMMs in one launch (48 blocks).
// ---------------------------------------------------------------------------
#define BK 16
__global__ __launch_bounds__(256) void k_small(
    const float* __restrict__ fmean, const float* __restrict__ ctx,
    const float* __restrict__ W_init_h, const float* __restrict__ W_init_c,
    const float* __restrict__ W_ih,
    const float* __restrict__ b_ih, const float* __restrict__ b_hh,
    float* __restrict__ hbuf, float* __restrict__ cbuf, float* __restrict__ gctx,
    unsigned short* __restrict__ h0_bf) {
  const float* A; const float* Bw; float* C;
  int ldb, ldc, n0;
  const float* bias1 = nullptr; const float* bias2 = nullptr;
  unsigned short* hb = nullptr;
  int bx = blockIdx.x;
  if (bx < 8)       { A = fmean; Bw = W_init_h; C = hbuf; ldb = VD_; ldc = HD_; n0 = bx * 64; hb = h0_bf; }
  else if (bx < 16) { A = fmean; Bw = W_init_c; C = cbuf; ldb = VD_; ldc = HD_; n0 = (bx - 8) * 64; }
  else { A = ctx; Bw = W_ih; C = gctx; ldb = VD_ + ED_; ldc = G4_; n0 = (bx - 16) * 64;
         bias1 = b_ih; bias2 = b_hh; }

  __shared__ float As[BK][64];
  __shared__ float Bs[BK][64];
  int tid = threadIdx.x;
  int tm = tid & 15, tn = tid >> 4;
  int sr = tid >> 2, sk = (tid & 3) * 4;
  const float* arow = A + (size_t)sr * VD_;
  const float* brow = Bw + (size_t)(n0 + sr) * ldb;
  float acc[4][4] = {};

  for (int k0 = 0; k0 < VD_; k0 += BK) {
    float4 av = *(const float4*)(arow + k0 + sk);
    float4 bv = *(const float4*)(brow + k0 + sk);
    __syncthreads();
    As[sk + 0][sr] = av.x; As[sk + 1][sr] = av.y;
    As[sk + 2][sr] = av.z; As[sk + 3][sr] = av.w;
    Bs[sk + 0][sr] = bv.x; Bs[sk + 1][sr] = bv.y;
    Bs[sk + 2][sr] = bv.z; Bs[sk + 3][sr] = bv.w;
    __syncthreads();
#pragma unroll
    for (int kk = 0; kk < BK; ++kk) {
      float4 a4 = *(const float4*)&As[kk][tm * 4];
      float4 b4 = *(const float4*)&Bs[kk][tn * 4];
      acc[0][0] += a4.x * b4.x; acc[0][1] += a4.x * b4.y; acc[0][2] += a4.x * b4.z; acc[0][3] += a4.x * b4.w;
      acc[1][0] += a4.y * b4.x; acc[1][1] += a4.y * b4.y; acc[1][2] += a4.y * b4.z; acc[1][3] += a4.y * b4.w;
      acc[2][0] += a4.z * b4.x; acc[2][1] += a4.z * b4.y; acc[2][2] += a4.z * b4.z; acc[2][3] += a4.z * b4.w;
      acc[3][0] += a4.w * b4.x; acc[3][1] += a4.w * b4.y; acc[3][2] += a4.w * b4.z; acc[3][3] += a4.w * b4.w;
    }
  }
#pragma unroll
  for (int j = 0; j < 4; ++j) {
    int n = n0 + tn * 4 + j;
    float bb = (bias1 ? bias1[n] + bias2[n] : 0.f);
#pragma unroll
    for (int i = 0; i < 4; ++i) {
      int mm = tm * 4 + i;
      float val = acc[i][j] + bb;
      C[(size_t)mm * ldc + n] = val;
      if (hb) hb[(size_t)mm * HD_ + n] = f2bf_(val);
    }
  }
}

// ---------------------------------------------------------------------------
// Staged bf16 MFMA GEMM: C[M,N] = A[M,K]@Bw[N,K]^T (+bias[n]) (+radd[m&63,n]).
// 128x128 block tile, BK=32, LDS-staged, 4 waves 2x2. (Used for gpre only.)
// ---------------------------------------------------------------------------
__global__ __launch_bounds__(256) void k_gemm_mfma(
    const unsigned short* __restrict__ A,
    const unsigned short* __restrict__ Bw,
    const float* __restrict__ bias,
    const float* __restrict__ radd, int ldr,
    float* __restrict__ C, int M, int Nn, int K) {
  __shared__ unsigned short As[128][32];
  __shared__ unsigned short Bs[128][32];
  int tid = threadIdx.x;
  int wave = tid >> 6, lane = tid & 63;
  int wm = wave & 1, wn = wave >> 1;
  int m0 = blockIdx.y * 128, n0 = blockIdx.x * 128;
  int l15 = lane & 15, quad = lane >> 4;
  int sr = tid >> 1, skq = (tid & 1) * 16;
  const unsigned short* ga = A + (size_t)(m0 + sr) * K + skq;
  int bn = n0 + sr; if (bn >= Nn) bn = Nn - 1;
  const unsigned short* gb = Bw + (size_t)bn * K + skq;

  f32x4 acc[4][4];
#pragma unroll
  for (int i = 0; i < 4; ++i)
#pragma unroll
    for (int j = 0; j < 4; ++j) acc[i][j] = (f32x4){0.f, 0.f, 0.f, 0.f};

  for (int k0 = 0; k0 < K; k0 += 32) {
    bf16x8 a0 = *(const bf16x8*)(ga + k0);
    bf16x8 a1 = *(const bf16x8*)(ga + k0 + 8);
    bf16x8 b0 = *(const bf16x8*)(gb + k0);
    bf16x8 b1 = *(const bf16x8*)(gb + k0 + 8);
    __syncthreads();
    *(bf16x8*)&As[sr][skq] = a0; *(bf16x8*)&As[sr][skq + 8] = a1;
    *(bf16x8*)&Bs[sr][skq] = b0; *(bf16x8*)&Bs[sr][skq + 8] = b1;
    __syncthreads();
    bf16x8 af[4], bfr[4];
#pragma unroll
    for (int mt = 0; mt < 4; ++mt)
      af[mt] = *(const bf16x8*)&As[wm * 64 + mt * 16 + l15][quad * 8];
#pragma unroll
    for (int nt = 0; nt < 4; ++nt)
      bfr[nt] = *(const bf16x8*)&Bs[wn * 64 + nt * 16 + l15][quad * 8];
#pragma unroll
    for (int mt = 0; mt < 4; ++mt)
#pragma unroll
      for (int nt = 0; nt < 4; ++nt)
        acc[mt][nt] = __builtin_amdgcn_mfma_f32_16x16x32_bf16(af[mt], bfr[nt], acc[mt][nt], 0, 0, 0);
  }

#pragma unroll
  for (int nt = 0; nt < 4; ++nt) {
    int n = n0 + wn * 64 + nt * 16 + l15;
    if (n < Nn) {
      float bb = bias ? bias[n] : 0.f;
#pragma unroll
      for (int mt = 0; mt < 4; ++mt) {
        int mbase = m0 + wm * 64 + mt * 16 + quad * 4;
#pragma unroll
        for (int r = 0; r < 4; ++r) {
          int mg = mbase + r;
          float ra = radd ? radd[(size_t)(mg & 63) * ldr + n] : 0.f;
          C[(size_t)mg * Nn + n] = acc[mt][nt][r] + bb + ra;
        }
      }
    }
  }
}

// ---------------------------------------------------------------------------
// Mega-kernel (R3-proven, byte-identical): 32 LSTM blocks (v3 recurrence) +
// WNW logits-worker blocks, ONE launch. Workers consume hall[t] as the LSTM
// publishes it (gated on the per-block step flags), computing
// logits = hall@W_out^T + b_out on the 224 otherwise-idle CUs.
// ---------------------------------------------------------------------------
__global__ __launch_bounds__(256, 1) void k_lstm_logits(
    const unsigned short* __restrict__ whh_bf,   // [2048][512] bf16
    const float* __restrict__ gpre,              // [T*64][2048]
    const unsigned short* __restrict__ h0_bf,    // [64][512] bf16
    const float* __restrict__ c0,                // [64][512] fp32
    unsigned short* __restrict__ hall_bf,        // [T][64][512] bf16
    int* __restrict__ bar,                       // [32*16] flags, 64B stride
    const unsigned short* __restrict__ wout_bf,  // [10000][512] bf16
    const float* __restrict__ b_out,             // [10000]
    float* __restrict__ logits) {                // [T*64][10000] fp32
  __shared__ unsigned short smem[64 * 512];      // lstm: whh 64KB; worker: As+Bs 16KB
  int bx = blockIdx.x;
  int tid = threadIdx.x;
  int wave = tid >> 6, lane = tid & 63;
  int l15 = lane & 15, quad = lane >> 4;

  if (bx < LSTM_NBLK) {
    // ======================= LSTM path (v3) ================================
    int w = wave;
    int n0 = bx * 16;

    // stage whh slice into LDS, one-time, XOR-swizzled
    for (int idx = tid; idx < 4096; idx += 256) {
      int r = idx >> 6, gg = idx & 63;
      int gate = r >> 4, l = r & 15;
      bf16x8 v = *(const bf16x8*)(whh_bf +
          (size_t)(gate * HD_ + n0 + l) * HD_ + gg * 8);
      *(bf16x8*)&smem[r * 512 + (gg ^ (r & 7)) * 8] = v;
    }

    int brow = w * 16 + quad * 4;

    float c_reg[4];
#pragma unroll
    for (int r = 0; r < 4; ++r)
      c_reg[r] = c0[(size_t)(brow + r) * HD_ + n0 + l15];

    float gr[16];
#pragma unroll
    for (int g = 0; g < 4; ++g)
#pragma unroll
      for (int r = 0; r < 4; ++r)
        gr[g * 4 + r] = gpre[(size_t)(brow + r) * G4_ + g * HD_ + n0 + l15];

    __syncthreads();   // whh ready

    for (int t = 0; t < T_; ++t) {
      const unsigned short* h_in =
          (t == 0) ? h0_bf : (hall_bf + (size_t)(t - 1) * B_ * HD_);
      const unsigned short* ar = h_in + (size_t)(w * 16 + l15) * HD_ + quad * 8;

      bf16x8 a[16];
#pragma unroll
      for (int ki = 0; ki < 16; ++ki)
        asm volatile("global_load_dwordx4 %0, %1, off sc0 sc1"
                     : "=v"(a[ki]) : "v"(ar + ki * 32) : "memory");
      asm volatile("s_waitcnt vmcnt(0)" ::: "memory");
      __builtin_amdgcn_sched_barrier(0);

      f32x4 acc[4];
#pragma unroll
      for (int i = 0; i < 4; ++i) acc[i] = (f32x4){0.f, 0.f, 0.f, 0.f};

#pragma unroll
      for (int ki = 0; ki < 16; ++ki) {
        int rb = l15 * 512 + (((ki * 4 + quad) ^ (l15 & 7)) << 3);
#pragma unroll
        for (int nt = 0; nt < 4; ++nt) {
          bf16x8 b = *(const bf16x8*)&smem[nt * 16 * 512 + rb];
          acc[nt] = __builtin_amdgcn_mfma_f32_16x16x32_bf16(a[ki], b, acc[nt], 0, 0, 0);
        }
      }

      unsigned short* hout = hall_bf + (size_t)t * B_ * HD_;
#pragma unroll
      for (int r = 0; r < 4; ++r) {
        float gi = acc[0][r] + gr[0 + r];
        float gf = acc[1][r] + gr[4 + r];
        float gg = acc[2][r] + gr[8 + r];
        float go = acc[3][r] + gr[12 + r];
        float cn = sigmoidf_(gf) * c_reg[r] + sigmoidf_(gi) * tanh_fast(gg);
        c_reg[r] = cn;
        unsigned hv = f2bf_(sigmoidf_(go) * tanh_fast(cn));
        unsigned short* sp = hout + (size_t)(brow + r) * HD_ + n0 + l15;
        asm volatile("global_store_short %0, %1, off sc0 sc1"
                     :: "v"(sp), "v"(hv) : "memory");
      }

      asm volatile("s_waitcnt vmcnt(0)" ::: "memory");  // h at coherence pt
      __syncthreads();                                  // all waves drained
      if (tid == 0) {
        int* fp = bar + bx * 16;
        int fv = t + 1;
        asm volatile("global_store_dword %0, %1, off sc0 sc1"
                     :: "v"(fp), "v"(fv) : "memory");
      }
      if (t < T_ - 1) {
        // prefetch gpre for t+1 — overlaps the barrier wait
        const float* gpt = gpre + (size_t)(t + 1) * B_ * G4_;
#pragma unroll
        for (int g = 0; g < 4; ++g)
#pragma unroll
          for (int r = 0; r < 4; ++r)
            gr[g * 4 + r] = gpt[(size_t)(brow + r) * G4_ + g * HD_ + n0 + l15];
        if (tid < 64) {   // wave 0: lanes 0..31 watch one flag each
          int* fp = bar + (tid & 31) * 16;
          while (true) {
            int v = __hip_atomic_load(fp, __ATOMIC_RELAXED,
                                      __HIP_MEMORY_SCOPE_AGENT);
            if (__all(v >= t + 1)) break;
            __builtin_amdgcn_s_sleep(1);
          }
        }
        __syncthreads();
      }
    }
  } else {
    // ===================== logits worker path ==============================
    int wq = bx - LSTM_NBLK;
    unsigned short (*As)[32] = (unsigned short (*)[32])smem;
    unsigned short (*Bs)[32] = (unsigned short (*)[32])(smem + 128 * 32);
    int wm = wave & 1, wn = wave >> 1;
    int sr = tid >> 1, skq = (tid & 1) * 16;

    for (int q = wq; q < NITEM; q += WNW) {
      int mt_ = q / 79, vt = q - mt_ * 79;
      int m0 = mt_ * 128, n0 = vt * 128;
      int tneed = (m0 >> 6) + 2;

      if (tid < 64) {
        const int* fp = bar + (tid & 31) * 16;
        while (true) {
          int v = __hip_atomic_load(fp, __ATOMIC_RELAXED,
                                    __HIP_MEMORY_SCOPE_AGENT);
          if (__all(v >= tneed)) break;
          __builtin_amdgcn_s_sleep(16);
        }
      }
      __syncthreads();

      const unsigned short* ga = hall_bf + (size_t)(m0 + sr) * HD_ + skq;
      int bn = n0 + sr; if (bn >= V_) bn = V_ - 1;
      const unsigned short* gb = wout_bf + (size_t)bn * HD_ + skq;

      f32x4 acc[4][4];
#pragma unroll
      for (int i = 0; i < 4; ++i)
#pragma unroll
        for (int j = 0; j < 4; ++j) acc[i][j] = (f32x4){0.f, 0.f, 0.f, 0.f};

      for (int k0 = 0; k0 < HD_; k0 += 32) {
        bf16x8 a0, a1, b0v, b1v;
        // hall written sc0sc1 by LSTM -> read from coherence point
        asm volatile("global_load_dwordx4 %0, %1, off sc0 sc1"
                     : "=v"(a0) : "v"(ga + k0) : "memory");
        asm volatile("global_load_dwordx4 %0, %1, off sc0 sc1"
                     : "=v"(a1) : "v"(ga + k0 + 8) : "memory");
        b0v = *(const bf16x8*)(gb + k0);
        b1v = *(const bf16x8*)(gb + k0 + 8);
        asm volatile("s_waitcnt vmcnt(0)" ::: "memory");
        __syncthreads();
        *(bf16x8*)&As[sr][skq] = a0; *(bf16x8*)&As[sr][skq + 8] = a1;
        *(bf16x8*)&Bs[sr][skq] = b0v; *(bf16x8*)&Bs[sr][skq + 8] = b1v;
        __syncthreads();
        bf16x8 af[4], bfr[4];
#pragma unroll
        for (int mt = 0; mt < 4; ++mt)
          af[mt] = *(const bf16x8*)&As[wm * 64 + mt * 16 + l15][quad * 8];
#pragma unroll
        for (int nt = 0; nt < 4; ++nt)
          bfr[nt] = *(const bf16x8*)&Bs[wn * 64 + nt * 16 + l15][quad * 8];
#pragma unroll
        for (int mt = 0; mt < 4; ++mt)
#pragma unroll
          for (int nt = 0; nt < 4; ++nt)
            acc[mt][nt] = __builtin_amdgcn_mfma_f32_16x16x32_bf16(
                af[mt], bfr[nt], acc[mt][nt], 0, 0, 0);
      }

#pragma unroll
      for (int nt = 0; nt < 4; ++nt) {
        int n = n0 + wn * 64 + nt * 16 + l15;
        if (n < V_) {
          float bb = b_out[n];
#pragma unroll
          for (int mt = 0; mt < 4; ++mt) {
            int mbase = m0 + wm * 64 + mt * 16 + quad * 4;
#pragma unroll
            for (int r = 0; r < 4; ++r) {
              int mg = mbase + r;
              logits[(size_t)mg * V_ + n] = acc[mt][nt][r] + bb;
            }
          }
        }
      }
    }
  }
}

// ---------------------------------------------------------------------------
// Fused log_softmax + softmax per row of logits [1280][10000] — ONE read
// pass: whole row register-resident (10 f32x4/thread), max + sum + both
// writes from registers. (Old version read logits 3x.)
// ---------------------------------------------------------------------------
__global__ __launch_bounds__(256) void k_softmax(float* __restrict__ logits,
                                                 float* __restrict__ out1) {
  __shared__ float red[8];
  int row = blockIdx.x, tid = threadIdx.x;
  int lane = tid & 63, wid = tid >> 6;
  float* lr = logits + (size_t)row * V_;
  float* o1 = out1 + (size_t)row * V_;

  f32x4 vv[10];
#pragma unroll
  for (int k = 0; k < 10; ++k) {
    int i = tid + 256 * k;
    if (i < 2500) vv[k] = *(const f32x4*)(lr + 4 * i);
    else          vv[k] = (f32x4){-1e30f, -1e30f, -1e30f, -1e30f};
  }

  float m = -1e30f;
#pragma unroll
  for (int k = 0; k < 10; ++k)
    m = fmaxf(m, fmaxf(fmaxf(vv[k][0], vv[k][1]), fmaxf(vv[k][2], vv[k][3])));
#pragma unroll
  for (int off = 32; off > 0; off >>= 1) m = fmaxf(m, __shfl_down(m, off, 64));
  if (lane == 0) red[4 + wid] = m;
  __syncthreads();
  m = fmaxf(fmaxf(red[4], red[5]), fmaxf(red[6], red[7]));

  float s = 0.f;
#pragma unroll
  for (int k = 0; k < 10; ++k)
    s += __expf(vv[k][0] - m) + __expf(vv[k][1] - m)
       + __expf(vv[k][2] - m) + __expf(vv[k][3] - m);
#pragma unroll
  for (int off = 32; off > 0; off >>= 1) s += __shfl_down(s, off, 64);
  if (lane == 0) red[wid] = s;
  __syncthreads();
  s = red[0] + red[1] + red[2] + red[3];
  float ls = __logf(s), inv = 1.f / s;

#pragma unroll
  for (int k = 0; k < 10; ++k) {
    int i = tid + 256 * k;
    if (i < 2500) {
      f32x4 v = vv[k], aa, bb;
#pragma unroll
      for (int j = 0; j < 4; ++j) {
        aa[j] = v[j] - m - ls;
        bb[j] = __expf(v[j] - m) * inv;
      }
      *(f32x4*)(o1 + 4 * i) = aa;   // log_softmax
      *(f32x4*)(lr + 4 * i) = bb;   // softmax in place
    }
  }
}

// ---------------------------------------------------------------------------
extern "C" void kernel_launch(void* const* d_in, const int* in_sizes, int n_in,
                              void* d_out, int out_size, void* d_ws, size_t ws_size,
                              hipStream_t stream) {
  const float* features = (const float*)d_in[0];
  const int*   captions = (const int*)d_in[1];
  const float* W_init_h = (const float*)d_in[2];
  const float* W_init_c = (const float*)d_in[3];
  const float* W_av     = (const float*)d_in[4];
  // d_in[5] b_av, d_in[6] W_ah, d_in[7] b_ah: cancel inside softmax over n.
  const float* embed    = (const float*)d_in[8];
  const float* W_ih     = (const float*)d_in[9];
  const float* W_hh     = (const float*)d_in[10];
  const float* b_ih     = (const float*)d_in[11];
  const float* b_hh     = (const float*)d_in[12];
  const float* W_out    = (const float*)d_in[13];
  const float* b_out    = (const float*)d_in[14];

  float* ws    = (float*)d_ws;
  float* fmean = ws;                             // 32768
  float* ctx   = fmean + B_ * VD_;               // 32768
  float* hbuf  = ctx + B_ * VD_;                 // 32768 (fp32 h0)
  float* cbuf  = hbuf + B_ * HD_;                // 32768 (c0)
  float* gctx  = cbuf + B_ * HD_;                // 131072
  float* svg   = gctx + (size_t)B_ * G4_;        // 12544 -> pad 12608
  float* gpre  = svg + 12608;                    // 2,621,440
  int*   bar   = (int*)(gpre + (size_t)T_ * B_ * G4_);                       // 512 ints (32 flags, 64B stride)
  unsigned short* wout_bf = (unsigned short*)(bar + 512);                    // 5,120,000
  unsigned short* wihe_bf = wout_bf + (size_t)V_ * HD_;                      // 1,048,576
  unsigned short* whh_bf  = wihe_bf + (size_t)G4_ * ED_;                     // 1,048,576
  unsigned short* emb_bf  = whh_bf + (size_t)G4_ * HD_;                      // 655,360
  unsigned short* h0_bf   = emb_bf + (size_t)T_ * B_ * ED_;                  // 32,768
  unsigned short* hall_bf = h0_bf + (size_t)B_ * HD_;                        // 655,360
  // total ~28.8 MB

  float* out1   = (float*)d_out;                     // log_softmax [T,B,V]
  float* logits = out1 + (size_t)T_ * B_ * V_;       // softmax slot = scratch

  hipMemsetAsync(bar, 0, 2048, stream);

  k_prep<<<7944, 256, 0, stream>>>(W_out, W_ih, W_hh, embed, captions,
                                   features, W_av,
                                   wout_bf, wihe_bf, whh_bf, emb_bf, svg);
  k_attn2<<<dim3(B_, 4), 256, 0, stream>>>(features, svg, fmean, ctx);
  k_small<<<48, 256, 0, stream>>>(fmean, ctx, W_init_h, W_init_c, W_ih,
                                  b_ih, b_hh, hbuf, cbuf, gctx, h0_bf);

  // gpre[t*64+b, :] = emb_bf @ wihe_bf^T + gctx[b, :]  (gctx includes biases)
  k_gemm_mfma<<<dim3(G4_ / 128, (T_ * B_) / 128), 256, 0, stream>>>(
      emb_bf, wihe_bf, nullptr, gctx, G4_, gpre, T_ * B_, G4_, ED_);

  // LSTM (32 persistent blocks) + logits GEMM (224 flag-gated workers),
  // ONE launch: logits compute hides under the recurrence's exchange idle.
  k_lstm_logits<<<LSTM_NBLK + WNW, 256, 0, stream>>>(
      whh_bf, gpre, h0_bf, cbuf, hall_bf, bar, wout_bf, b_out, logits);

  k_softmax<<<T_ * B_, 256, 0, stream>>>(logits, out1);
}